// Round 2
// baseline (2663.766 us; speedup 1.0000x reference)
//
#include <hip/hip_runtime.h>
#include <math.h>

#define T_ROWS 512
#define V_NUM  256
#define F_NUM  64
#define D_DIM  512
#define NM_EPS 1e-6f
#define LNE    1e-5f
#define ETA    0.015f

__device__ __forceinline__ float wave_sum(float x) {
#pragma unroll
  for (int off = 32; off > 0; off >>= 1) x += __shfl_xor(x, off);
  return x;
}

// ---------------- LayerNorm over last dim (512); one wave per row ----------
__global__ __launch_bounds__(256) void ln_kernel(
    const float* __restrict__ in, const float* __restrict__ w,
    const float* __restrict__ b, float* __restrict__ out, int rows) {
  int lane = threadIdx.x & 63;
  int row  = (blockIdx.x << 2) + (threadIdx.x >> 6);
  if (row >= rows) return;
  const float4* x4 = (const float4*)(in + (size_t)row * D_DIM);
  float4 v0 = x4[lane * 2 + 0];
  float4 v1 = x4[lane * 2 + 1];
  float s = v0.x + v0.y + v0.z + v0.w + v1.x + v1.y + v1.z + v1.w;
  s = wave_sum(s);
  float m = s * (1.0f / D_DIM);
  float d0 = v0.x - m, d1 = v0.y - m, d2 = v0.z - m, d3 = v0.w - m;
  float d4 = v1.x - m, d5 = v1.y - m, d6 = v1.z - m, d7 = v1.w - m;
  float q = d0*d0 + d1*d1 + d2*d2 + d3*d3 + d4*d4 + d5*d5 + d6*d6 + d7*d7;
  q = wave_sum(q);
  float rstd = rsqrtf(q * (1.0f / D_DIM) + LNE);
  const float4* w4 = (const float4*)w;
  const float4* b4 = (const float4*)b;
  float4 W0 = w4[lane*2+0], W1 = w4[lane*2+1];
  float4 B0 = b4[lane*2+0], B1 = b4[lane*2+1];
  float4 o0, o1;
  o0.x = d0*rstd*W0.x + B0.x; o0.y = d1*rstd*W0.y + B0.y;
  o0.z = d2*rstd*W0.z + B0.z; o0.w = d3*rstd*W0.w + B0.w;
  o1.x = d4*rstd*W1.x + B1.x; o1.y = d5*rstd*W1.y + B1.y;
  o1.z = d6*rstd*W1.z + B1.z; o1.w = d7*rstd*W1.w + B1.w;
  float4* y4 = (float4*)(out + (size_t)row * D_DIM);
  y4[lane*2+0] = o0; y4[lane*2+1] = o1;
}

// ---------------- transpose proj_w (512x512) -> Wt[k][j] = W[j][k] ---------
__global__ __launch_bounds__(256) void transpose_kernel(
    const float* __restrict__ W, float* __restrict__ Wt) {
  __shared__ float tile[64][65];
  int bx = blockIdx.x * 64;   // W col block (= Wt row block)
  int by = blockIdx.y * 64;   // W row block (= Wt col block)
  int tid = threadIdx.x;
#pragma unroll
  for (int l = 0; l < 4; ++l) {
    int idx = l * 256 + tid;
    int r = idx >> 4, c = (idx & 15) * 4;
    float4 v = *(const float4*)(W + (size_t)(by + r) * D_DIM + bx + c);
    tile[r][c+0] = v.x; tile[r][c+1] = v.y; tile[r][c+2] = v.z; tile[r][c+3] = v.w;
  }
  __syncthreads();
#pragma unroll
  for (int l = 0; l < 4; ++l) {
    int idx = l * 256 + tid;
    int r = idx >> 4, c = (idx & 15) * 4;
    float4 v = make_float4(tile[c+0][r], tile[c+1][r], tile[c+2][r], tile[c+3][r]);
    *(float4*)(Wt + (size_t)(bx + r) * D_DIM + by + c) = v;
  }
}

// ---------------- sims[v][t][f] = sum_d t_ln[t][d] * vd[v][f][d] -----------
// grid (T/64, V), block 256, tile 64x64, K-tiles of 64, 4x4 per thread
__global__ __launch_bounds__(256) void sims_kernel(
    const float* __restrict__ tmat, const float* __restrict__ vd,
    float* __restrict__ sims) {
  __shared__ float As[64][65];
  __shared__ float Bs[64][65];
  int v = blockIdx.y, mt = blockIdx.x;
  int tid = threadIdx.x;
  int trow = tid >> 4, tcol = tid & 15;
  const float* A = tmat + (size_t)mt * 64 * D_DIM;
  const float* B = vd + (size_t)v * F_NUM * D_DIM;
  float acc[4][4] = {};
  for (int k0 = 0; k0 < D_DIM; k0 += 64) {
#pragma unroll
    for (int l = 0; l < 4; ++l) {
      int idx = l * 256 + tid;
      int r = idx >> 4, c = (idx & 15) * 4;
      float4 av = *(const float4*)(A + (size_t)r * D_DIM + k0 + c);
      As[r][c+0] = av.x; As[r][c+1] = av.y; As[r][c+2] = av.z; As[r][c+3] = av.w;
      float4 bv = *(const float4*)(B + (size_t)r * D_DIM + k0 + c);
      Bs[r][c+0] = bv.x; Bs[r][c+1] = bv.y; Bs[r][c+2] = bv.z; Bs[r][c+3] = bv.w;
    }
    __syncthreads();
#pragma unroll 8
    for (int k = 0; k < 64; ++k) {
      float a0 = As[trow*4+0][k], a1 = As[trow*4+1][k];
      float a2 = As[trow*4+2][k], a3 = As[trow*4+3][k];
      float b0 = Bs[tcol*4+0][k], b1 = Bs[tcol*4+1][k];
      float b2 = Bs[tcol*4+2][k], b3 = Bs[tcol*4+3][k];
      acc[0][0] += a0*b0; acc[0][1] += a0*b1; acc[0][2] += a0*b2; acc[0][3] += a0*b3;
      acc[1][0] += a1*b0; acc[1][1] += a1*b1; acc[1][2] += a1*b2; acc[1][3] += a1*b3;
      acc[2][0] += a2*b0; acc[2][1] += a2*b1; acc[2][2] += a2*b2; acc[2][3] += a2*b3;
      acc[3][0] += a3*b0; acc[3][1] += a3*b1; acc[3][2] += a3*b2; acc[3][3] += a3*b3;
    }
    __syncthreads();
  }
  float* C = sims + ((size_t)v * T_ROWS + mt * 64) * F_NUM;
#pragma unroll
  for (int i = 0; i < 4; ++i) {
    float4 o = make_float4(acc[i][0], acc[i][1], acc[i][2], acc[i][3]);
    *(float4*)(C + (size_t)(trow*4+i) * F_NUM + tcol*4) = o;
  }
}

// ---------------- gram[v][m][n] = sum_d vd[v][m][d]*vd[v][n][d] ------------
__global__ __launch_bounds__(256) void gram_kernel(
    const float* __restrict__ vd, float* __restrict__ gram) {
  __shared__ float As[64][65];
  int v = blockIdx.x;
  int tid = threadIdx.x;
  int trow = tid >> 4, tcol = tid & 15;
  const float* A = vd + (size_t)v * F_NUM * D_DIM;
  float acc[4][4] = {};
  for (int k0 = 0; k0 < D_DIM; k0 += 64) {
#pragma unroll
    for (int l = 0; l < 4; ++l) {
      int idx = l * 256 + tid;
      int r = idx >> 4, c = (idx & 15) * 4;
      float4 av = *(const float4*)(A + (size_t)r * D_DIM + k0 + c);
      As[r][c+0] = av.x; As[r][c+1] = av.y; As[r][c+2] = av.z; As[r][c+3] = av.w;
    }
    __syncthreads();
#pragma unroll 8
    for (int k = 0; k < 64; ++k) {
      float a0 = As[trow*4+0][k], a1 = As[trow*4+1][k];
      float a2 = As[trow*4+2][k], a3 = As[trow*4+3][k];
      float b0 = As[tcol*4+0][k], b1 = As[tcol*4+1][k];
      float b2 = As[tcol*4+2][k], b3 = As[tcol*4+3][k];
      acc[0][0] += a0*b0; acc[0][1] += a0*b1; acc[0][2] += a0*b2; acc[0][3] += a0*b3;
      acc[1][0] += a1*b0; acc[1][1] += a1*b1; acc[1][2] += a1*b2; acc[1][3] += a1*b3;
      acc[2][0] += a2*b0; acc[2][1] += a2*b1; acc[2][2] += a2*b2; acc[2][3] += a2*b3;
      acc[3][0] += a3*b0; acc[3][1] += a3*b1; acc[3][2] += a3*b2; acc[3][3] += a3*b3;
    }
    __syncthreads();
  }
  float* C = gram + (size_t)v * 4096;
#pragma unroll
  for (int i = 0; i < 4; ++i) {
    float4 o = make_float4(acc[i][0], acc[i][1], acc[i][2], acc[i][3]);
    *(float4*)(C + (size_t)(trow*4+i) * F_NUM + tcol*4) = o;
  }
}

// ---------------- NMF: 10 iters + quad-form normalization ------------------
// one block per v, 512 threads, thread t owns row t of a[512][64]
// a lives in LDS (stride 65 -> only 2-way conflicts, free); dnm/sims in VGPRs
__global__ __launch_bounds__(512, 2) void nmf_kernel(
    const float* __restrict__ gram, float* __restrict__ attn) {
  __shared__ float G[64 * 64];      // 16 KiB, symmetric
  __shared__ float A[512 * 65];     // 130 KiB
  int tid = threadIdx.x;
  int v = blockIdx.x;
  const float4* g4 = (const float4*)(gram + (size_t)v * 4096);
  ((float4*)G)[tid]       = g4[tid];
  ((float4*)G)[512 + tid] = g4[512 + tid];
  float* ar = &A[tid * 65];
  const float* srow = attn + ((size_t)v * T_ROWS + tid) * F_NUM;
  float s[64];
#pragma unroll
  for (int q = 0; q < 16; ++q) {
    float4 t4 = ((const float4*)srow)[q];
    s[q*4+0] = t4.x; s[q*4+1] = t4.y; s[q*4+2] = t4.z; s[q*4+3] = t4.w;
    ar[q*4+0] = t4.x; ar[q*4+1] = t4.y; ar[q*4+2] = t4.z; ar[q*4+3] = t4.w;
  }
  __syncthreads();
  for (int it = 0; it < 10; ++it) {
    float dnm[64];
#pragma unroll
    for (int m = 0; m < 64; ++m) dnm[m] = 0.0f;
    for (int n = 0; n < 64; ++n) {
      float an = ar[n];
      const float* gr = &G[n * 64];                    // gram symmetric
#pragma unroll
      for (int m = 0; m < 64; ++m) dnm[m] += an * gr[m];
    }
#pragma unroll
    for (int m = 0; m < 64; ++m) {
      float xv = ar[m] - ETA * ((dnm[m] + NM_EPS) - s[m]);
      ar[m] = (xv <= 0.0f) ? NM_EPS : xv;
    }
  }
  // ||a @ vd||^2 == a^T gram a  (exact: gram bitwise symmetric)
  float t2[64];
#pragma unroll
  for (int m = 0; m < 64; ++m) t2[m] = 0.0f;
  for (int n = 0; n < 64; ++n) {
    float an = ar[n];
    const float* gr = &G[n * 64];
#pragma unroll
    for (int m = 0; m < 64; ++m) t2[m] += an * gr[m];
  }
  float n2 = 0.0f;
#pragma unroll
  for (int m = 0; m < 64; ++m) n2 += ar[m] * t2[m];
  float inv = 1.0f / sqrtf(n2);
  float* orow = attn + ((size_t)v * T_ROWS + tid) * F_NUM;
#pragma unroll
  for (int q = 0; q < 16; ++q) {
    float4 o = make_float4(ar[q*4+0]*inv, ar[q*4+1]*inv, ar[q*4+2]*inv, ar[q*4+3]*inv);
    ((float4*)orow)[q] = o;
  }
}

// ---------------- attn_out = attn_v @ vd_v, fused LN2 -> d_out -------------
// grid (16, V): 32 rows/block, full 512 cols, K=64. block 256 = 4 rg x 64 cg
__global__ __launch_bounds__(256) void attnout_kernel(
    const float* __restrict__ attn, const float* __restrict__ vd,
    const float* __restrict__ w2, const float* __restrict__ b2,
    float* __restrict__ out) {
  __shared__ float as_[32][64];     // 8 KiB
  __shared__ float vs_[64][512];    // 128 KiB
  int v = blockIdx.y;
  int t0 = blockIdx.x * 32;
  int tid = threadIdx.x;
  int rg = tid >> 6, cg = tid & 63;
  const float4* A4 = (const float4*)(attn + ((size_t)v * T_ROWS + t0) * F_NUM);
#pragma unroll
  for (int l = 0; l < 2; ++l) ((float4*)as_)[l*256+tid] = A4[l*256+tid];
  const float4* B4 = (const float4*)(vd + (size_t)v * F_NUM * D_DIM);
#pragma unroll
  for (int l = 0; l < 32; ++l) ((float4*)vs_)[l*256+tid] = B4[l*256+tid];
  __syncthreads();
  float acc[8][8];
#pragma unroll
  for (int i = 0; i < 8; ++i)
#pragma unroll
    for (int e = 0; e < 8; ++e) acc[i][e] = 0.0f;
#pragma unroll 4
  for (int k = 0; k < 64; ++k) {
    float4 w0 = *(const float4*)&vs_[k][cg*4];
    float4 w1 = *(const float4*)&vs_[k][cg*4 + 256];
#pragma unroll
    for (int i = 0; i < 8; ++i) {
      float av = as_[rg*8+i][k];
      acc[i][0] += av*w0.x; acc[i][1] += av*w0.y; acc[i][2] += av*w0.z; acc[i][3] += av*w0.w;
      acc[i][4] += av*w1.x; acc[i][5] += av*w1.y; acc[i][6] += av*w1.z; acc[i][7] += av*w1.w;
    }
  }
  const float4* w24 = (const float4*)w2;
  const float4* b24 = (const float4*)b2;
  float4 W20 = w24[cg], W21 = w24[cg+64];
  float4 B20 = b24[cg], B21 = b24[cg+64];
#pragma unroll
  for (int i = 0; i < 8; ++i) {
    float s = acc[i][0]+acc[i][1]+acc[i][2]+acc[i][3]+acc[i][4]+acc[i][5]+acc[i][6]+acc[i][7];
    s = wave_sum(s);
    float m = s * (1.0f / D_DIM);
    float q = 0.0f;
#pragma unroll
    for (int e = 0; e < 8; ++e) { float d = acc[i][e] - m; q += d*d; }
    q = wave_sum(q);
    float rstd = rsqrtf(q * (1.0f / D_DIM) + LNE);
    float4 o0, o1;
    o0.x = (acc[i][0]-m)*rstd*W20.x + B20.x; o0.y = (acc[i][1]-m)*rstd*W20.y + B20.y;
    o0.z = (acc[i][2]-m)*rstd*W20.z + B20.z; o0.w = (acc[i][3]-m)*rstd*W20.w + B20.w;
    o1.x = (acc[i][4]-m)*rstd*W21.x + B21.x; o1.y = (acc[i][5]-m)*rstd*W21.y + B21.y;
    o1.z = (acc[i][6]-m)*rstd*W21.z + B21.z; o1.w = (acc[i][7]-m)*rstd*W21.w + B21.w;
    float4* dst = (float4*)(out + ((size_t)v * T_ROWS + t0 + rg*8 + i) * D_DIM);
    dst[cg] = o0; dst[cg+64] = o1;
  }
}

// ---------------- out = LN3(x + x@W^T + pb), in place on d_out -------------
// grid 4096: 32 rows/block, full 512 cols, K=512 dbuf-tiled by 16
__global__ __launch_bounds__(256) void final_kernel(
    const float* __restrict__ Wt, const float* __restrict__ pb,
    const float* __restrict__ w3, const float* __restrict__ b3,
    float* __restrict__ io) {
  __shared__ float xs[32][512];     // 64 KiB
  __shared__ float wt[2][16][512];  // 64 KiB
  int tid = threadIdx.x;
  int rg = tid >> 6, cg = tid & 63;
  size_t row0 = (size_t)blockIdx.x * 32;
  const float4* src = (const float4*)(io + row0 * D_DIM);
#pragma unroll
  for (int l = 0; l < 16; ++l) ((float4*)xs)[l*256+tid] = src[l*256+tid];
  const float4* w0src = (const float4*)Wt;
#pragma unroll
  for (int l = 0; l < 8; ++l) ((float4*)wt[0])[l*256+tid] = w0src[l*256+tid];
  __syncthreads();
  float acc[8][8];
#pragma unroll
  for (int i = 0; i < 8; ++i)
#pragma unroll
    for (int e = 0; e < 8; ++e) acc[i][e] = 0.0f;
  int buf = 0;
  for (int kt = 0; kt < 32; ++kt) {
    float4 pre[8];
    if (kt < 31) {
      const float4* nsrc = (const float4*)(Wt + (size_t)(kt+1) * 16 * D_DIM);
#pragma unroll
      for (int l = 0; l < 8; ++l) pre[l] = nsrc[l*256+tid];
    }
#pragma unroll
    for (int kk = 0; kk < 16; ++kk) {
      int k = kt*16 + kk;
      float4 w0 = *(const float4*)&wt[buf][kk][cg*4];
      float4 w1 = *(const float4*)&wt[buf][kk][cg*4 + 256];
#pragma unroll
      for (int i = 0; i < 8; ++i) {
        float xv = xs[rg*8+i][k];
        acc[i][0] += xv*w0.x; acc[i][1] += xv*w0.y; acc[i][2] += xv*w0.z; acc[i][3] += xv*w0.w;
        acc[i][4] += xv*w1.x; acc[i][5] += xv*w1.y; acc[i][6] += xv*w1.z; acc[i][7] += xv*w1.w;
      }
    }
    if (kt < 31) {
#pragma unroll
      for (int l = 0; l < 8; ++l) ((float4*)wt[buf^1])[l*256+tid] = pre[l];
    }
    __syncthreads();
    buf ^= 1;
  }
  const float4* pb4 = (const float4*)pb;
  const float4* w34 = (const float4*)w3;
  const float4* b34 = (const float4*)b3;
  float4 PB0 = pb4[cg], PB1 = pb4[cg+64];
  float4 W30 = w34[cg], W31 = w34[cg+64];
  float4 B30 = b34[cg], B31 = b34[cg+64];
#pragma unroll
  for (int i = 0; i < 8; ++i) {
    int r = rg*8 + i;
    float z[8];
    z[0] = xs[r][cg*4+0]   + acc[i][0] + PB0.x;
    z[1] = xs[r][cg*4+1]   + acc[i][1] + PB0.y;
    z[2] = xs[r][cg*4+2]   + acc[i][2] + PB0.z;
    z[3] = xs[r][cg*4+3]   + acc[i][3] + PB0.w;
    z[4] = xs[r][cg*4+256] + acc[i][4] + PB1.x;
    z[5] = xs[r][cg*4+257] + acc[i][5] + PB1.y;
    z[6] = xs[r][cg*4+258] + acc[i][6] + PB1.z;
    z[7] = xs[r][cg*4+259] + acc[i][7] + PB1.w;
    float s = z[0]+z[1]+z[2]+z[3]+z[4]+z[5]+z[6]+z[7];
    s = wave_sum(s);
    float m = s * (1.0f / D_DIM);
    float q = 0.0f;
#pragma unroll
    for (int e = 0; e < 8; ++e) { float d = z[e] - m; q += d*d; }
    q = wave_sum(q);
    float rstd = rsqrtf(q * (1.0f / D_DIM) + LNE);
    float4 o0, o1;
    o0.x = (z[0]-m)*rstd*W30.x + B30.x; o0.y = (z[1]-m)*rstd*W30.y + B30.y;
    o0.z = (z[2]-m)*rstd*W30.z + B30.z; o0.w = (z[3]-m)*rstd*W30.w + B30.w;
    o1.x = (z[4]-m)*rstd*W31.x + B31.x; o1.y = (z[5]-m)*rstd*W31.y + B31.y;
    o1.z = (z[6]-m)*rstd*W31.z + B31.z; o1.w = (z[7]-m)*rstd*W31.w + B31.w;
    float4* dst = (float4*)(io + (row0 + r) * D_DIM);
    dst[cg] = o0; dst[cg+64] = o1;
  }
}

extern "C" void kernel_launch(void* const* d_in, const int* in_sizes, int n_in,
                              void* d_out, int out_size, void* d_ws, size_t ws_size,
                              hipStream_t stream) {
  const float* text  = (const float*)d_in[0];
  const float* video = (const float*)d_in[1];
  const float* ln1w  = (const float*)d_in[2];
  const float* ln1b  = (const float*)d_in[3];
  const float* ln2w  = (const float*)d_in[4];
  const float* ln2b  = (const float*)d_in[5];
  const float* ln3w  = (const float*)d_in[6];
  const float* ln3b  = (const float*)d_in[7];
  const float* projw = (const float*)d_in[8];
  const float* projb = (const float*)d_in[9];
  float* out = (float*)d_out;
  float* ws  = (float*)d_ws;

  float* t_ln  = ws;                   // 512*512          = 262144 f
  float* vd_ln = t_ln + 262144;        // 256*64*512       = 8388608 f
  float* gram  = vd_ln + 8388608;      // 256*64*64        = 1048576 f
  float* attn  = gram + 1048576;       // 256*512*64       = 8388608 f
  float* Wt    = attn + 8388608;       // 512*512          = 262144 f
  // total 18,350,080 floats = 73.4 MB of d_ws

  ln_kernel<<<128, 256, 0, stream>>>(text, ln1w, ln1b, t_ln, 512);
  ln_kernel<<<4096, 256, 0, stream>>>(video, ln1w, ln1b, vd_ln, 16384);
  transpose_kernel<<<dim3(8, 8), 256, 0, stream>>>(projw, Wt);
  sims_kernel<<<dim3(8, 256), 256, 0, stream>>>(t_ln, vd_ln, attn);
  gram_kernel<<<256, 256, 0, stream>>>(vd_ln, gram);
  nmf_kernel<<<256, 512, 0, stream>>>(gram, attn);
  attnout_kernel<<<dim3(16, 256), 256, 0, stream>>>(attn, vd_ln, ln2w, ln2b, out);
  final_kernel<<<4096, 256, 0, stream>>>(Wt, projb, ln3w, ln3b, out);
}

// Round 3
// 1408.353 us; speedup vs baseline: 1.8914x; 1.8914x over previous
//
#include <hip/hip_runtime.h>
#include <math.h>

#define T_ROWS 512
#define V_NUM  256
#define F_NUM  64
#define D_DIM  512
#define NM_EPS 1e-6f
#define LNE    1e-5f
#define ETA    0.015f

typedef __attribute__((ext_vector_type(8))) short shortx8;
typedef __attribute__((ext_vector_type(4))) float floatx4;

__device__ __forceinline__ float wave_sum(float x) {
#pragma unroll
  for (int off = 32; off > 0; off >>= 1) x += __shfl_xor(x, off);
  return x;
}

// bf16 round-to-nearest-even (values finite, no NaN handling needed)
__device__ __forceinline__ uint32_t bf_hi(float f) {
  uint32_t u = __float_as_uint(f);
  return (u + 0x7fffu + ((u >> 16) & 1u)) >> 16;
}
__device__ __forceinline__ uint32_t packf(float f) {
  uint32_t h = bf_hi(f);
  float rem = f - __uint_as_float(h << 16);
  uint32_t l = bf_hi(rem);
  return (h << 16) | l;
}
__device__ __forceinline__ float unpackf(uint32_t p) {
  return __uint_as_float(p & 0xffff0000u) + __uint_as_float(p << 16);
}

// ---------------- LayerNorm over last dim (512); one wave per row ----------
__global__ __launch_bounds__(256) void ln_kernel(
    const float* __restrict__ in, const float* __restrict__ w,
    const float* __restrict__ b, float* __restrict__ out, int rows) {
  int lane = threadIdx.x & 63;
  int row  = (blockIdx.x << 2) + (threadIdx.x >> 6);
  if (row >= rows) return;
  const float4* x4 = (const float4*)(in + (size_t)row * D_DIM);
  float4 v0 = x4[lane * 2 + 0];
  float4 v1 = x4[lane * 2 + 1];
  float s = v0.x + v0.y + v0.z + v0.w + v1.x + v1.y + v1.z + v1.w;
  s = wave_sum(s);
  float m = s * (1.0f / D_DIM);
  float d0 = v0.x - m, d1 = v0.y - m, d2 = v0.z - m, d3 = v0.w - m;
  float d4 = v1.x - m, d5 = v1.y - m, d6 = v1.z - m, d7 = v1.w - m;
  float q = d0*d0 + d1*d1 + d2*d2 + d3*d3 + d4*d4 + d5*d5 + d6*d6 + d7*d7;
  q = wave_sum(q);
  float rstd = rsqrtf(q * (1.0f / D_DIM) + LNE);
  const float4* w4 = (const float4*)w;
  const float4* b4 = (const float4*)b;
  float4 W0 = w4[lane*2+0], W1 = w4[lane*2+1];
  float4 B0 = b4[lane*2+0], B1 = b4[lane*2+1];
  float4 o0, o1;
  o0.x = d0*rstd*W0.x + B0.x; o0.y = d1*rstd*W0.y + B0.y;
  o0.z = d2*rstd*W0.z + B0.z; o0.w = d3*rstd*W0.w + B0.w;
  o1.x = d4*rstd*W1.x + B1.x; o1.y = d5*rstd*W1.y + B1.y;
  o1.z = d6*rstd*W1.z + B1.z; o1.w = d7*rstd*W1.w + B1.w;
  float4* y4 = (float4*)(out + (size_t)row * D_DIM);
  y4[lane*2+0] = o0; y4[lane*2+1] = o1;
}

// ---------------- pack proj_w fp32 -> u32 (bf16 hi<<16 | lo) ---------------
__global__ __launch_bounds__(256) void convw_kernel(
    const float* __restrict__ W, uint32_t* __restrict__ Wp) {
  int i = (blockIdx.x * 256 + threadIdx.x) * 4;
  float4 v = *(const float4*)(W + i);
  uint4 o;
  o.x = packf(v.x); o.y = packf(v.y); o.z = packf(v.z); o.w = packf(v.w);
  *(uint4*)(Wp + i) = o;
}

// ---------------- sims[v][t][f] = sum_d t_ln[t][d] * vd[v][f][d] -----------
__global__ __launch_bounds__(256) void sims_kernel(
    const float* __restrict__ tmat, const float* __restrict__ vd,
    float* __restrict__ sims) {
  __shared__ float As[64][65];
  __shared__ float Bs[64][65];
  int v = blockIdx.y, mt = blockIdx.x;
  int tid = threadIdx.x;
  int trow = tid >> 4, tcol = tid & 15;
  const float* A = tmat + (size_t)mt * 64 * D_DIM;
  const float* B = vd + (size_t)v * F_NUM * D_DIM;
  float acc[4][4] = {};
  for (int k0 = 0; k0 < D_DIM; k0 += 64) {
#pragma unroll
    for (int l = 0; l < 4; ++l) {
      int idx = l * 256 + tid;
      int r = idx >> 4, c = (idx & 15) * 4;
      float4 av = *(const float4*)(A + (size_t)r * D_DIM + k0 + c);
      As[r][c+0] = av.x; As[r][c+1] = av.y; As[r][c+2] = av.z; As[r][c+3] = av.w;
      float4 bv = *(const float4*)(B + (size_t)r * D_DIM + k0 + c);
      Bs[r][c+0] = bv.x; Bs[r][c+1] = bv.y; Bs[r][c+2] = bv.z; Bs[r][c+3] = bv.w;
    }
    __syncthreads();
#pragma unroll 8
    for (int k = 0; k < 64; ++k) {
      float a0 = As[trow*4+0][k], a1 = As[trow*4+1][k];
      float a2 = As[trow*4+2][k], a3 = As[trow*4+3][k];
      float b0 = Bs[tcol*4+0][k], b1 = Bs[tcol*4+1][k];
      float b2 = Bs[tcol*4+2][k], b3 = Bs[tcol*4+3][k];
      acc[0][0] += a0*b0; acc[0][1] += a0*b1; acc[0][2] += a0*b2; acc[0][3] += a0*b3;
      acc[1][0] += a1*b0; acc[1][1] += a1*b1; acc[1][2] += a1*b2; acc[1][3] += a1*b3;
      acc[2][0] += a2*b0; acc[2][1] += a2*b1; acc[2][2] += a2*b2; acc[2][3] += a2*b3;
      acc[3][0] += a3*b0; acc[3][1] += a3*b1; acc[3][2] += a3*b2; acc[3][3] += a3*b3;
    }
    __syncthreads();
  }
  float* C = sims + ((size_t)v * T_ROWS + mt * 64) * F_NUM;
#pragma unroll
  for (int i = 0; i < 4; ++i) {
    float4 o = make_float4(acc[i][0], acc[i][1], acc[i][2], acc[i][3]);
    *(float4*)(C + (size_t)(trow*4+i) * F_NUM + tcol*4) = o;
  }
}

// ---------------- gram[v][m][n] = sum_d vd[v][m][d]*vd[v][n][d] ------------
__global__ __launch_bounds__(256) void gram_kernel(
    const float* __restrict__ vd, float* __restrict__ gram) {
  __shared__ float As[64][65];
  int v = blockIdx.x;
  int tid = threadIdx.x;
  int trow = tid >> 4, tcol = tid & 15;
  const float* A = vd + (size_t)v * F_NUM * D_DIM;
  float acc[4][4] = {};
  for (int k0 = 0; k0 < D_DIM; k0 += 64) {
#pragma unroll
    for (int l = 0; l < 4; ++l) {
      int idx = l * 256 + tid;
      int r = idx >> 4, c = (idx & 15) * 4;
      float4 av = *(const float4*)(A + (size_t)r * D_DIM + k0 + c);
      As[r][c+0] = av.x; As[r][c+1] = av.y; As[r][c+2] = av.z; As[r][c+3] = av.w;
    }
    __syncthreads();
#pragma unroll 8
    for (int k = 0; k < 64; ++k) {
      float a0 = As[trow*4+0][k], a1 = As[trow*4+1][k];
      float a2 = As[trow*4+2][k], a3 = As[trow*4+3][k];
      float b0 = As[tcol*4+0][k], b1 = As[tcol*4+1][k];
      float b2 = As[tcol*4+2][k], b3 = As[tcol*4+3][k];
      acc[0][0] += a0*b0; acc[0][1] += a0*b1; acc[0][2] += a0*b2; acc[0][3] += a0*b3;
      acc[1][0] += a1*b0; acc[1][1] += a1*b1; acc[1][2] += a1*b2; acc[1][3] += a1*b3;
      acc[2][0] += a2*b0; acc[2][1] += a2*b1; acc[2][2] += a2*b2; acc[2][3] += a2*b3;
      acc[3][0] += a3*b0; acc[3][1] += a3*b1; acc[3][2] += a3*b2; acc[3][3] += a3*b3;
    }
    __syncthreads();
  }
  float* C = gram + (size_t)v * 4096;
#pragma unroll
  for (int i = 0; i < 4; ++i) {
    float4 o = make_float4(acc[i][0], acc[i][1], acc[i][2], acc[i][3]);
    *(float4*)(C + (size_t)(trow*4+i) * F_NUM + tcol*4) = o;
  }
}

// ---------------- NMF: 10 iters + quad-form normalization ------------------
__global__ __launch_bounds__(512, 2) void nmf_kernel(
    const float* __restrict__ gram, float* __restrict__ attn) {
  __shared__ float G[64 * 64];      // 16 KiB, symmetric
  __shared__ float A[512 * 65];     // 130 KiB
  int tid = threadIdx.x;
  int v = blockIdx.x;
  const float4* g4 = (const float4*)(gram + (size_t)v * 4096);
  ((float4*)G)[tid]       = g4[tid];
  ((float4*)G)[512 + tid] = g4[512 + tid];
  float* ar = &A[tid * 65];
  const float* srow = attn + ((size_t)v * T_ROWS + tid) * F_NUM;
  float s[64];
#pragma unroll
  for (int q = 0; q < 16; ++q) {
    float4 t4 = ((const float4*)srow)[q];
    s[q*4+0] = t4.x; s[q*4+1] = t4.y; s[q*4+2] = t4.z; s[q*4+3] = t4.w;
    ar[q*4+0] = t4.x; ar[q*4+1] = t4.y; ar[q*4+2] = t4.z; ar[q*4+3] = t4.w;
  }
  __syncthreads();
  for (int it = 0; it < 10; ++it) {
    float dnm[64];
#pragma unroll
    for (int m = 0; m < 64; ++m) dnm[m] = 0.0f;
    for (int n = 0; n < 64; ++n) {
      float an = ar[n];
      const float* gr = &G[n * 64];
#pragma unroll
      for (int m = 0; m < 64; ++m) dnm[m] += an * gr[m];
    }
#pragma unroll
    for (int m = 0; m < 64; ++m) {
      float xv = ar[m] - ETA * ((dnm[m] + NM_EPS) - s[m]);
      ar[m] = (xv <= 0.0f) ? NM_EPS : xv;
    }
  }
  // ||a @ vd||^2 == a^T gram a  (exact: gram bitwise symmetric)
  float t2[64];
#pragma unroll
  for (int m = 0; m < 64; ++m) t2[m] = 0.0f;
  for (int n = 0; n < 64; ++n) {
    float an = ar[n];
    const float* gr = &G[n * 64];
#pragma unroll
    for (int m = 0; m < 64; ++m) t2[m] += an * gr[m];
  }
  float n2 = 0.0f;
#pragma unroll
  for (int m = 0; m < 64; ++m) n2 += ar[m] * t2[m];
  float inv = 1.0f / sqrtf(n2);
  float* orow = attn + ((size_t)v * T_ROWS + tid) * F_NUM;
#pragma unroll
  for (int q = 0; q < 16; ++q) {
    float4 o = make_float4(ar[q*4+0]*inv, ar[q*4+1]*inv, ar[q*4+2]*inv, ar[q*4+3]*inv);
    ((float4*)orow)[q] = o;
  }
}

// ---------------- attn_out = attn_v @ vd_v, fused LN2 -> packed d_out ------
__global__ __launch_bounds__(256) void attnout_kernel(
    const float* __restrict__ attn, const float* __restrict__ vd,
    const float* __restrict__ w2, const float* __restrict__ b2,
    uint32_t* __restrict__ out) {
  __shared__ float as_[32][64];     // 8 KiB
  __shared__ float vs_[64][512];    // 128 KiB
  int v = blockIdx.y;
  int t0 = blockIdx.x * 32;
  int tid = threadIdx.x;
  int rg = tid >> 6, cg = tid & 63;
  const float4* A4 = (const float4*)(attn + ((size_t)v * T_ROWS + t0) * F_NUM);
#pragma unroll
  for (int l = 0; l < 2; ++l) ((float4*)as_)[l*256+tid] = A4[l*256+tid];
  const float4* B4 = (const float4*)(vd + (size_t)v * F_NUM * D_DIM);
#pragma unroll
  for (int l = 0; l < 32; ++l) ((float4*)vs_)[l*256+tid] = B4[l*256+tid];
  __syncthreads();
  float acc[8][8];
#pragma unroll
  for (int i = 0; i < 8; ++i)
#pragma unroll
    for (int e = 0; e < 8; ++e) acc[i][e] = 0.0f;
#pragma unroll 4
  for (int k = 0; k < 64; ++k) {
    float4 w0 = *(const float4*)&vs_[k][cg*4];
    float4 w1 = *(const float4*)&vs_[k][cg*4 + 256];
#pragma unroll
    for (int i = 0; i < 8; ++i) {
      float av = as_[rg*8+i][k];
      acc[i][0] += av*w0.x; acc[i][1] += av*w0.y; acc[i][2] += av*w0.z; acc[i][3] += av*w0.w;
      acc[i][4] += av*w1.x; acc[i][5] += av*w1.y; acc[i][6] += av*w1.z; acc[i][7] += av*w1.w;
    }
  }
  const float4* w24 = (const float4*)w2;
  const float4* b24 = (const float4*)b2;
  float4 W20 = w24[cg], W21 = w24[cg+64];
  float4 B20 = b24[cg], B21 = b24[cg+64];
#pragma unroll
  for (int i = 0; i < 8; ++i) {
    float s = acc[i][0]+acc[i][1]+acc[i][2]+acc[i][3]+acc[i][4]+acc[i][5]+acc[i][6]+acc[i][7];
    s = wave_sum(s);
    float m = s * (1.0f / D_DIM);
    float q = 0.0f;
#pragma unroll
    for (int e = 0; e < 8; ++e) { float d = acc[i][e] - m; q += d*d; }
    q = wave_sum(q);
    float rstd = rsqrtf(q * (1.0f / D_DIM) + LNE);
    uint4 p0, p1;
    p0.x = packf((acc[i][0]-m)*rstd*W20.x + B20.x);
    p0.y = packf((acc[i][1]-m)*rstd*W20.y + B20.y);
    p0.z = packf((acc[i][2]-m)*rstd*W20.z + B20.z);
    p0.w = packf((acc[i][3]-m)*rstd*W20.w + B20.w);
    p1.x = packf((acc[i][4]-m)*rstd*W21.x + B21.x);
    p1.y = packf((acc[i][5]-m)*rstd*W21.y + B21.y);
    p1.z = packf((acc[i][6]-m)*rstd*W21.z + B21.z);
    p1.w = packf((acc[i][7]-m)*rstd*W21.w + B21.w);
    uint4* dst = (uint4*)(out + ((size_t)v * T_ROWS + t0 + rg*8 + i) * D_DIM);
    dst[cg] = p0; dst[cg+64] = p1;
  }
}

// ---------------- out = LN3(x + x@W^T + pb), split-bf16 MFMA, in place -----
// x packed in io (u32 hi/lo bf16). 2048 blocks x 256 thr. Tile 64 rows x 512
// cols, BK=32, 16 K-steps. LDS XOR-octet swizzle: pos = oct ^ ((row>>1)&3).
// A/B frag: row = lane&15, k = (lane>>4)*8 + j (contiguous). C: col = lane&15,
// row = (lane>>4)*4 + reg (m89/m91-verified).
__global__ __launch_bounds__(256, 2) void fgemm_kernel(
    const uint32_t* __restrict__ Wp, const float* __restrict__ pb,
    const float* __restrict__ w3, const float* __restrict__ b3,
    uint32_t* __restrict__ io) {
  __shared__ unsigned short Bs_h[512 * 32];   // 32 KiB
  __shared__ unsigned short Bs_l[512 * 32];   // 32 KiB
  __shared__ unsigned short As_h[64 * 32];    // 4 KiB
  __shared__ unsigned short As_l[64 * 32];    // 4 KiB
  __shared__ float red_s[64][4];
  __shared__ float red_q[64][4];
  __shared__ float tot_m[64];
  __shared__ float tot_r[64];

  const int tid = threadIdx.x;
  const int lane = tid & 63;
  const int wv = tid >> 6;           // wave 0..3 -> col block of 128
  const int l15 = lane & 15;
  const int l4 = lane >> 4;          // 0..3
  const int wn0 = wv * 128;
  const size_t row0 = (size_t)blockIdx.x * 64;

  floatx4 acc[4][8];
#pragma unroll
  for (int m = 0; m < 4; ++m)
#pragma unroll
    for (int n = 0; n < 8; ++n) acc[m][n] = (floatx4){0.f, 0.f, 0.f, 0.f};

  for (int kt = 0; kt < 16; ++kt) {
    const int k0 = kt * 32;
    // ---- stage B tile: W rows 0..511, k0..k0+31, unpack hi/lo, swizzled
#pragma unroll
    for (int q = 0; q < 16; ++q) {
      int Q = q * 256 + tid;
      int row = Q >> 3, qk = Q & 7;
      const uint4 pv = *(const uint4*)(Wp + (size_t)row * 512 + k0 + qk * 4);
      uint32_t h0 = (pv.x >> 16) | (pv.y & 0xffff0000u);
      uint32_t h1 = (pv.z >> 16) | (pv.w & 0xffff0000u);
      uint32_t l0 = (pv.x & 0xffffu) | (pv.y << 16);
      uint32_t l1 = (pv.z & 0xffffu) | (pv.w << 16);
      int oct = qk >> 1, sub = qk & 1;
      int pos = oct ^ ((row >> 1) & 3);
      int ha = row * 32 + pos * 8 + sub * 4;
      *(uint2*)&Bs_h[ha] = make_uint2(h0, h1);
      *(uint2*)&Bs_l[ha] = make_uint2(l0, l1);
    }
    // ---- stage A tile: 64 rows x 32 k from packed io
    {
      int arow = tid >> 2, aq = tid & 3;
      const uint32_t* src = io + (row0 + arow) * 512 + k0 + aq * 8;
      uint4 u0 = *(const uint4*)(src);
      uint4 u1 = *(const uint4*)(src + 4);
      uint32_t hh0 = (u0.x >> 16) | (u0.y & 0xffff0000u);
      uint32_t hh1 = (u0.z >> 16) | (u0.w & 0xffff0000u);
      uint32_t hh2 = (u1.x >> 16) | (u1.y & 0xffff0000u);
      uint32_t hh3 = (u1.z >> 16) | (u1.w & 0xffff0000u);
      uint32_t ll0 = (u0.x & 0xffffu) | (u0.y << 16);
      uint32_t ll1 = (u0.z & 0xffffu) | (u0.w << 16);
      uint32_t ll2 = (u1.x & 0xffffu) | (u1.y << 16);
      uint32_t ll3 = (u1.z & 0xffffu) | (u1.w << 16);
      int pos = aq ^ ((arow >> 1) & 3);
      int ha = arow * 32 + pos * 8;
      *(uint2*)&As_h[ha]     = make_uint2(hh0, hh1);
      *(uint2*)&As_h[ha + 4] = make_uint2(hh2, hh3);
      *(uint2*)&As_l[ha]     = make_uint2(ll0, ll1);
      *(uint2*)&As_l[ha + 4] = make_uint2(ll2, ll3);
    }
    __syncthreads();
    // ---- compute: 96 MFMA per wave per K-step
    shortx8 afh[4], afl[4];
#pragma unroll
    for (int m = 0; m < 4; ++m) {
      int ra = m * 16 + l15;
      int pa = l4 ^ ((ra >> 1) & 3);
      afh[m] = *(const shortx8*)&As_h[ra * 32 + pa * 8];
      afl[m] = *(const shortx8*)&As_l[ra * 32 + pa * 8];
    }
#pragma unroll
    for (int n = 0; n < 8; ++n) {
      int rb = wn0 + n * 16 + l15;
      int pk = l4 ^ ((rb >> 1) & 3);
      shortx8 bfh = *(const shortx8*)&Bs_h[rb * 32 + pk * 8];
      shortx8 bfl = *(const shortx8*)&Bs_l[rb * 32 + pk * 8];
#pragma unroll
      for (int m = 0; m < 4; ++m) {
        acc[m][n] = __builtin_amdgcn_mfma_f32_16x16x32_bf16(afh[m], bfh, acc[m][n], 0, 0, 0);
        acc[m][n] = __builtin_amdgcn_mfma_f32_16x16x32_bf16(afl[m], bfh, acc[m][n], 0, 0, 0);
        acc[m][n] = __builtin_amdgcn_mfma_f32_16x16x32_bf16(afh[m], bfl, acc[m][n], 0, 0, 0);
      }
    }
    __syncthreads();
  }

  // ---- epilogue: z = x + gemm + pb; fused LN3; write fp32 over io ----
  float pbv[8], w3v[8], b3v[8];
#pragma unroll
  for (int n = 0; n < 8; ++n) {
    int col = wn0 + n * 16 + l15;
    pbv[n] = pb[col]; w3v[n] = w3[col]; b3v[n] = b3[col];
  }
  float ps[4][4], pq[4][4];
#pragma unroll
  for (int m = 0; m < 4; ++m)
#pragma unroll
    for (int r = 0; r < 4; ++r) { ps[m][r] = 0.f; pq[m][r] = 0.f; }
#pragma unroll
  for (int m = 0; m < 4; ++m) {
#pragma unroll
    for (int r = 0; r < 4; ++r) {
      int rowz = m * 16 + l4 * 4 + r;
#pragma unroll
      for (int n = 0; n < 8; ++n) {
        uint32_t xp = io[(row0 + rowz) * 512 + wn0 + n * 16 + l15];
        float z = unpackf(xp) + acc[m][n][r] + pbv[n];
        acc[m][n][r] = z;
        ps[m][r] += z;
        pq[m][r] += z * z;
      }
    }
  }
  // reduce across the 16 lanes sharing each row
#pragma unroll
  for (int m = 0; m < 4; ++m) {
#pragma unroll
    for (int r = 0; r < 4; ++r) {
      float s = ps[m][r], q = pq[m][r];
      s += __shfl_xor(s, 1); s += __shfl_xor(s, 2);
      s += __shfl_xor(s, 4); s += __shfl_xor(s, 8);
      q += __shfl_xor(q, 1); q += __shfl_xor(q, 2);
      q += __shfl_xor(q, 4); q += __shfl_xor(q, 8);
      if (l15 == 0) {
        red_s[m * 16 + l4 * 4 + r][wv] = s;
        red_q[m * 16 + l4 * 4 + r][wv] = q;
      }
    }
  }
  __syncthreads();
  if (tid < 64) {
    float s = red_s[tid][0] + red_s[tid][1] + red_s[tid][2] + red_s[tid][3];
    float q = red_q[tid][0] + red_q[tid][1] + red_q[tid][2] + red_q[tid][3];
    float mean = s * (1.0f / D_DIM);
    float var = q * (1.0f / D_DIM) - mean * mean;
    tot_m[tid] = mean;
    tot_r[tid] = rsqrtf(var + LNE);
  }
  __syncthreads();
  float* of = (float*)io;
#pragma unroll
  for (int m = 0; m < 4; ++m) {
#pragma unroll
    for (int r = 0; r < 4; ++r) {
      int rowz = m * 16 + l4 * 4 + r;
      float mean = tot_m[rowz], rstd = tot_r[rowz];
#pragma unroll
      for (int n = 0; n < 8; ++n) {
        of[(row0 + rowz) * 512 + wn0 + n * 16 + l15] =
            (acc[m][n][r] - mean) * rstd * w3v[n] + b3v[n];
      }
    }
  }
}

extern "C" void kernel_launch(void* const* d_in, const int* in_sizes, int n_in,
                              void* d_out, int out_size, void* d_ws, size_t ws_size,
                              hipStream_t stream) {
  const float* text  = (const float*)d_in[0];
  const float* video = (const float*)d_in[1];
  const float* ln1w  = (const float*)d_in[2];
  const float* ln1b  = (const float*)d_in[3];
  const float* ln2w  = (const float*)d_in[4];
  const float* ln2b  = (const float*)d_in[5];
  const float* ln3w  = (const float*)d_in[6];
  const float* ln3b  = (const float*)d_in[7];
  const float* projw = (const float*)d_in[8];
  const float* projb = (const float*)d_in[9];
  float* ws  = (float*)d_ws;

  float* t_ln  = ws;                   // 512*512          = 262144 f
  float* vd_ln = t_ln + 262144;        // 256*64*512       = 8388608 f
  float* gram  = vd_ln + 8388608;      // 256*64*64        = 1048576 f
  float* attn  = gram + 1048576;       // 256*512*64       = 8388608 f
  uint32_t* Wp = (uint32_t*)(attn + 8388608);  // 512*512 u32 (packed bf16 hi/lo)
  // total 18,350,080 x 4B = 73.4 MB of d_ws

  ln_kernel<<<128, 256, 0, stream>>>(text, ln1w, ln1b, t_ln, 512);
  ln_kernel<<<4096, 256, 0, stream>>>(video, ln1w, ln1b, vd_ln, 16384);
  convw_kernel<<<256, 256, 0, stream>>>(projw, Wp);
  sims_kernel<<<dim3(8, 256), 256, 0, stream>>>(t_ln, vd_ln, attn);
  gram_kernel<<<256, 256, 0, stream>>>(vd_ln, gram);
  nmf_kernel<<<256, 512, 0, stream>>>(gram, attn);
  attnout_kernel<<<dim3(16, 256), 256, 0, stream>>>(attn, vd_ln, ln2w, ln2b,
                                                    (uint32_t*)d_out);
  fgemm_kernel<<<2048, 256, 0, stream>>>(Wp, projb, ln3w, ln3b, (uint32_t*)d_out);
}

// Round 5
// 1342.523 us; speedup vs baseline: 1.9841x; 1.0490x over previous
//
#include <hip/hip_runtime.h>
#include <math.h>

#define T_ROWS 512
#define V_NUM  256
#define F_NUM  64
#define D_DIM  512
#define NM_EPS 1e-6f
#define LNE    1e-5f
#define ETA    0.015f

typedef __attribute__((ext_vector_type(8))) short shortx8;
typedef __attribute__((ext_vector_type(4))) float floatx4;

__device__ __forceinline__ float wave_sum(float x) {
#pragma unroll
  for (int off = 32; off > 0; off >>= 1) x += __shfl_xor(x, off);
  return x;
}

// bf16 round-to-nearest-even split helpers
__device__ __forceinline__ uint32_t bf_hi(float f) {
  uint32_t u = __float_as_uint(f);
  return (u + 0x7fffu + ((u >> 16) & 1u)) >> 16;
}
__device__ __forceinline__ uint32_t packf(float f) {
  uint32_t h = bf_hi(f);
  float rem = f - __uint_as_float(h << 16);
  uint32_t l = bf_hi(rem);
  return (h << 16) | l;
}
__device__ __forceinline__ float unpackf(uint32_t p) {
  return __uint_as_float(p & 0xffff0000u) + __uint_as_float(p << 16);
}
// 8 packed u32 (8 k-elements) -> hi/lo shortx8 MFMA fragments
__device__ __forceinline__ void unpack8(uint4 a, uint4 b, shortx8* h, shortx8* l) {
  uint4 hu, lu;
  hu.x = (a.x >> 16) | (a.y & 0xffff0000u);
  hu.y = (a.z >> 16) | (a.w & 0xffff0000u);
  hu.z = (b.x >> 16) | (b.y & 0xffff0000u);
  hu.w = (b.z >> 16) | (b.w & 0xffff0000u);
  lu.x = (a.x & 0xffffu) | (a.y << 16);
  lu.y = (a.z & 0xffffu) | (a.w << 16);
  lu.z = (b.x & 0xffffu) | (b.y << 16);
  lu.w = (b.z & 0xffffu) | (b.w << 16);
  *h = *(shortx8*)&hu;
  *l = *(shortx8*)&lu;
}

// ---------------- LayerNorm over last dim (512); one wave per row ----------
__global__ __launch_bounds__(256) void ln_kernel(
    const float* __restrict__ in, const float* __restrict__ w,
    const float* __restrict__ b, float* __restrict__ out, int rows) {
  int lane = threadIdx.x & 63;
  int row  = (blockIdx.x << 2) + (threadIdx.x >> 6);
  if (row >= rows) return;
  const float4* x4 = (const float4*)(in + (size_t)row * D_DIM);
  float4 v0 = x4[lane * 2 + 0];
  float4 v1 = x4[lane * 2 + 1];
  float s = v0.x + v0.y + v0.z + v0.w + v1.x + v1.y + v1.z + v1.w;
  s = wave_sum(s);
  float m = s * (1.0f / D_DIM);
  float d0 = v0.x - m, d1 = v0.y - m, d2 = v0.z - m, d3 = v0.w - m;
  float d4 = v1.x - m, d5 = v1.y - m, d6 = v1.z - m, d7 = v1.w - m;
  float q = d0*d0 + d1*d1 + d2*d2 + d3*d3 + d4*d4 + d5*d5 + d6*d6 + d7*d7;
  q = wave_sum(q);
  float rstd = rsqrtf(q * (1.0f / D_DIM) + LNE);
  const float4* w4 = (const float4*)w;
  const float4* b4 = (const float4*)b;
  float4 W0 = w4[lane*2+0], W1 = w4[lane*2+1];
  float4 B0 = b4[lane*2+0], B1 = b4[lane*2+1];
  float4 o0, o1;
  o0.x = d0*rstd*W0.x + B0.x; o0.y = d1*rstd*W0.y + B0.y;
  o0.z = d2*rstd*W0.z + B0.z; o0.w = d3*rstd*W0.w + B0.w;
  o1.x = d4*rstd*W1.x + B1.x; o1.y = d5*rstd*W1.y + B1.y;
  o1.z = d6*rstd*W1.z + B1.z; o1.w = d7*rstd*W1.w + B1.w;
  float4* y4 = (float4*)(out + (size_t)row * D_DIM);
  y4[lane*2+0] = o0; y4[lane*2+1] = o1;
}

// ---------------- pack proj_w fp32 -> u32 (bf16 hi<<16 | lo) ---------------
__global__ __launch_bounds__(256) void convw_kernel(
    const float* __restrict__ W, uint32_t* __restrict__ Wp) {
  int i = (blockIdx.x * 256 + threadIdx.x) * 4;
  float4 v = *(const float4*)(W + i);
  uint4 o;
  o.x = packf(v.x); o.y = packf(v.y); o.z = packf(v.z); o.w = packf(v.w);
  *(uint4*)(Wp + i) = o;
}

// ---------------- sims[v][t][f] = sum_d t_ln[t][d] * vd[v][f][d] -----------
__global__ __launch_bounds__(256) void sims_kernel(
    const float* __restrict__ tmat, const float* __restrict__ vd,
    float* __restrict__ sims) {
  __shared__ float As[64][65];
  __shared__ float Bs[64][65];
  int v = blockIdx.y, mt = blockIdx.x;
  int tid = threadIdx.x;
  int trow = tid >> 4, tcol = tid & 15;
  const float* A = tmat + (size_t)mt * 64 * D_DIM;
  const float* B = vd + (size_t)v * F_NUM * D_DIM;
  float acc[4][4] = {};
  for (int k0 = 0; k0 < D_DIM; k0 += 64) {
#pragma unroll
    for (int l = 0; l < 4; ++l) {
      int idx = l * 256 + tid;
      int r = idx >> 4, c = (idx & 15) * 4;
      float4 av = *(const float4*)(A + (size_t)r * D_DIM + k0 + c);
      As[r][c+0] = av.x; As[r][c+1] = av.y; As[r][c+2] = av.z; As[r][c+3] = av.w;
      float4 bv = *(const float4*)(B + (size_t)r * D_DIM + k0 + c);
      Bs[r][c+0] = bv.x; Bs[r][c+1] = bv.y; Bs[r][c+2] = bv.z; Bs[r][c+3] = bv.w;
    }
    __syncthreads();
#pragma unroll 8
    for (int k = 0; k < 64; ++k) {
      float a0 = As[trow*4+0][k], a1 = As[trow*4+1][k];
      float a2 = As[trow*4+2][k], a3 = As[trow*4+3][k];
      float b0 = Bs[tcol*4+0][k], b1 = Bs[tcol*4+1][k];
      float b2 = Bs[tcol*4+2][k], b3 = Bs[tcol*4+3][k];
      acc[0][0] += a0*b0; acc[0][1] += a0*b1; acc[0][2] += a0*b2; acc[0][3] += a0*b3;
      acc[1][0] += a1*b0; acc[1][1] += a1*b1; acc[1][2] += a1*b2; acc[1][3] += a1*b3;
      acc[2][0] += a2*b0; acc[2][1] += a2*b1; acc[2][2] += a2*b2; acc[2][3] += a2*b3;
      acc[3][0] += a3*b0; acc[3][1] += a3*b1; acc[3][2] += a3*b2; acc[3][3] += a3*b3;
    }
    __syncthreads();
  }
  float* C = sims + ((size_t)v * T_ROWS + mt * 64) * F_NUM;
#pragma unroll
  for (int i = 0; i < 4; ++i) {
    float4 o = make_float4(acc[i][0], acc[i][1], acc[i][2], acc[i][3]);
    *(float4*)(C + (size_t)(trow*4+i) * F_NUM + tcol*4) = o;
  }
}

// ---------------- gram[v][m][n] = sum_d vd[v][m][d]*vd[v][n][d] ------------
__global__ __launch_bounds__(256) void gram_kernel(
    const float* __restrict__ vd, float* __restrict__ gram) {
  __shared__ float As[64][65];
  int v = blockIdx.x;
  int tid = threadIdx.x;
  int trow = tid >> 4, tcol = tid & 15;
  const float* A = vd + (size_t)v * F_NUM * D_DIM;
  float acc[4][4] = {};
  for (int k0 = 0; k0 < D_DIM; k0 += 64) {
#pragma unroll
    for (int l = 0; l < 4; ++l) {
      int idx = l * 256 + tid;
      int r = idx >> 4, c = (idx & 15) * 4;
      float4 av = *(const float4*)(A + (size_t)r * D_DIM + k0 + c);
      As[r][c+0] = av.x; As[r][c+1] = av.y; As[r][c+2] = av.z; As[r][c+3] = av.w;
    }
    __syncthreads();
#pragma unroll 8
    for (int k = 0; k < 64; ++k) {
      float a0 = As[trow*4+0][k], a1 = As[trow*4+1][k];
      float a2 = As[trow*4+2][k], a3 = As[trow*4+3][k];
      float b0 = As[tcol*4+0][k], b1 = As[tcol*4+1][k];
      float b2 = As[tcol*4+2][k], b3 = As[tcol*4+3][k];
      acc[0][0] += a0*b0; acc[0][1] += a0*b1; acc[0][2] += a0*b2; acc[0][3] += a0*b3;
      acc[1][0] += a1*b0; acc[1][1] += a1*b1; acc[1][2] += a1*b2; acc[1][3] += a1*b3;
      acc[2][0] += a2*b0; acc[2][1] += a2*b1; acc[2][2] += a2*b2; acc[2][3] += a2*b3;
      acc[3][0] += a3*b0; acc[3][1] += a3*b1; acc[3][2] += a3*b2; acc[3][3] += a3*b3;
    }
    __syncthreads();
  }
  float* C = gram + (size_t)v * 4096;
#pragma unroll
  for (int i = 0; i < 4; ++i) {
    float4 o = make_float4(acc[i][0], acc[i][1], acc[i][2], acc[i][3]);
    *(float4*)(C + (size_t)(trow*4+i) * F_NUM + tcol*4) = o;
  }
}

// ---------------- vdt: in-place per-v transpose+pack -----------------------
// vd_ln[v] (64f x 512d fp32) -> same memory as (512d x 64f u32 packed)
__global__ __launch_bounds__(256) void vdt_kernel(float* __restrict__ vd) {
  __shared__ float tile[64][513];   // ~131.3 KiB
  int v = blockIdx.x;
  int tid = threadIdx.x;
  float* base = vd + (size_t)v * F_NUM * D_DIM;
#pragma unroll
  for (int p = 0; p < 32; ++p) {
    int idx = p * 256 + tid;
    int f = idx >> 7, dq = (idx & 127) * 4;
    float4 x = *(const float4*)(base + (size_t)f * D_DIM + dq);
    tile[f][dq+0] = x.x; tile[f][dq+1] = x.y; tile[f][dq+2] = x.z; tile[f][dq+3] = x.w;
  }
  __syncthreads();
  uint32_t* out = (uint32_t*)base;
#pragma unroll
  for (int p = 0; p < 32; ++p) {
    int idx = p * 256 + tid;
    int d = idx >> 4, fq = (idx & 15) * 4;
    uint4 o;
    o.x = packf(tile[fq+0][d]); o.y = packf(tile[fq+1][d]);
    o.z = packf(tile[fq+2][d]); o.w = packf(tile[fq+3][d]);
    *(uint4*)(out + (size_t)d * F_NUM + fq) = o;
  }
}

// ---------------- NMF: 10 iters + quad-form norm; emits PACKED attn --------
__global__ __launch_bounds__(512, 2) void nmf_kernel(
    const float* __restrict__ gram, const float* __restrict__ sims_in,
    uint32_t* __restrict__ attn_out) {
  __shared__ float G[64 * 64];      // 16 KiB, symmetric
  __shared__ float A[512 * 65];     // 130 KiB
  int tid = threadIdx.x;
  int v = blockIdx.x;
  const float4* g4 = (const float4*)(gram + (size_t)v * 4096);
  ((float4*)G)[tid]       = g4[tid];
  ((float4*)G)[512 + tid] = g4[512 + tid];
  float* ar = &A[tid * 65];
  const float* srow = sims_in + ((size_t)v * T_ROWS + tid) * F_NUM;
  float s[64];
#pragma unroll
  for (int q = 0; q < 16; ++q) {
    float4 t4 = ((const float4*)srow)[q];
    s[q*4+0] = t4.x; s[q*4+1] = t4.y; s[q*4+2] = t4.z; s[q*4+3] = t4.w;
    ar[q*4+0] = t4.x; ar[q*4+1] = t4.y; ar[q*4+2] = t4.z; ar[q*4+3] = t4.w;
  }
  __syncthreads();
  for (int it = 0; it < 10; ++it) {
    float dnm[64];
#pragma unroll
    for (int m = 0; m < 64; ++m) dnm[m] = 0.0f;
    for (int n = 0; n < 64; ++n) {
      float an = ar[n];
      const float* gr = &G[n * 64];
#pragma unroll
      for (int m = 0; m < 64; ++m) dnm[m] += an * gr[m];
    }
#pragma unroll
    for (int m = 0; m < 64; ++m) {
      float xv = ar[m] - ETA * ((dnm[m] + NM_EPS) - s[m]);
      ar[m] = (xv <= 0.0f) ? NM_EPS : xv;
    }
  }
  // ||a @ vd||^2 == a^T gram a  (exact: gram bitwise symmetric)
  float t2[64];
#pragma unroll
  for (int m = 0; m < 64; ++m) t2[m] = 0.0f;
  for (int n = 0; n < 64; ++n) {
    float an = ar[n];
    const float* gr = &G[n * 64];
#pragma unroll
    for (int m = 0; m < 64; ++m) t2[m] += an * gr[m];
  }
  float n2 = 0.0f;
#pragma unroll
  for (int m = 0; m < 64; ++m) n2 += ar[m] * t2[m];
  float inv = 1.0f / sqrtf(n2);
  uint32_t* orow = attn_out + ((size_t)v * T_ROWS + tid) * F_NUM;
#pragma unroll
  for (int q = 0; q < 16; ++q) {
    uint4 o;
    o.x = packf(ar[q*4+0]*inv); o.y = packf(ar[q*4+1]*inv);
    o.z = packf(ar[q*4+2]*inv); o.w = packf(ar[q*4+3]*inv);
    *(uint4*)(orow + q*4) = o;
  }
}

// ---------------- attn_out = attn_v @ vd_v (MFMA), fused LN2 -> packed out -
// grid (8, V): 64 t-rows/block, all 512 d-cols, K=64 (2 steps of 32).
// Barrier-free main loop; frags streamed from global (L2-warm), unpacked.
__global__ __launch_bounds__(256, 2) void attnout_kernel(
    const uint32_t* __restrict__ attnp, const uint32_t* __restrict__ vdTp,
    const float* __restrict__ w2, const float* __restrict__ b2,
    uint32_t* __restrict__ out) {
  __shared__ float red_s[64][4];
  __shared__ float red_q[64][4];
  __shared__ float tot_m[64];
  __shared__ float tot_r[64];
  const int tid = threadIdx.x;
  const int lane = tid & 63;
  const int wv = tid >> 6;
  const int l15 = lane & 15;
  const int l4 = lane >> 4;
  const int wn0 = wv * 128;
  const int v = blockIdx.y;
  const int row0 = blockIdx.x * 64;

  const uint32_t* aB = attnp + ((size_t)v * T_ROWS + row0 + l15) * F_NUM + l4 * 8;
  const uint32_t* bB = vdTp + ((size_t)v * D_DIM + wn0 + l15) * F_NUM + l4 * 8;

  floatx4 acc[4][8];
#pragma unroll
  for (int m = 0; m < 4; ++m)
#pragma unroll
    for (int n = 0; n < 8; ++n) acc[m][n] = (floatx4){0.f, 0.f, 0.f, 0.f};

#pragma unroll
  for (int ks = 0; ks < 2; ++ks) {
    const int k0 = ks * 32;
    shortx8 afh[4], afl[4];
#pragma unroll
    for (int m = 0; m < 4; ++m) {
      const uint32_t* p = aB + m * (16 * F_NUM) + k0;
      unpack8(*(const uint4*)p, *(const uint4*)(p + 4), &afh[m], &afl[m]);
    }
#pragma unroll
    for (int n = 0; n < 8; ++n) {
      const uint32_t* q = bB + n * (16 * F_NUM) + k0;
      shortx8 bfh, bfl;
      unpack8(*(const uint4*)q, *(const uint4*)(q + 4), &bfh, &bfl);
#pragma unroll
      for (int m = 0; m < 4; ++m) {
        acc[m][n] = __builtin_amdgcn_mfma_f32_16x16x32_bf16(afh[m], bfh, acc[m][n], 0, 0, 0);
        acc[m][n] = __builtin_amdgcn_mfma_f32_16x16x32_bf16(afl[m], bfh, acc[m][n], 0, 0, 0);
        acc[m][n] = __builtin_amdgcn_mfma_f32_16x16x32_bf16(afh[m], bfl, acc[m][n], 0, 0, 0);
      }
    }
  }

  // fused LN2 over rows of 512, then pack to u32 out
  float w2v[8], b2v[8];
#pragma unroll
  for (int n = 0; n < 8; ++n) {
    int col = wn0 + n * 16 + l15;
    w2v[n] = w2[col]; b2v[n] = b2[col];
  }
  float ps[4][4], pq[4][4];
#pragma unroll
  for (int m = 0; m < 4; ++m)
#pragma unroll
    for (int r = 0; r < 4; ++r) { ps[m][r] = 0.f; pq[m][r] = 0.f; }
#pragma unroll
  for (int m = 0; m < 4; ++m)
#pragma unroll
    for (int r = 0; r < 4; ++r)
#pragma unroll
      for (int n = 0; n < 8; ++n) {
        float z = acc[m][n][r];
        ps[m][r] += z; pq[m][r] += z * z;
      }
#pragma unroll
  for (int m = 0; m < 4; ++m)
#pragma unroll
    for (int r = 0; r < 4; ++r) {
      float s = ps[m][r], q = pq[m][r];
      s += __shfl_xor(s, 1); s += __shfl_xor(s, 2);
      s += __shfl_xor(s, 4); s += __shfl_xor(s, 8);
      q += __shfl_xor(q, 1); q += __shfl_xor(q, 2);
      q += __shfl_xor(q, 4); q += __shfl_xor(q, 8);
      if (l15 == 0) {
        red_s[m * 16 + l4 * 4 + r][wv] = s;
        red_q[m * 16 + l4 * 4 + r][wv] = q;
      }
    }
  __syncthreads();
  if (tid < 64) {
    float s = red_s[tid][0] + red_s[tid][1] + red_s[tid][2] + red_s[tid][3];
    float q = red_q[tid][0] + red_q[tid][1] + red_q[tid][2] + red_q[tid][3];
    float mean = s * (1.0f / D_DIM);
    float var = q * (1.0f / D_DIM) - mean * mean;
    tot_m[tid] = mean;
    tot_r[tid] = rsqrtf(var + LNE);
  }
  __syncthreads();
#pragma unroll
  for (int m = 0; m < 4; ++m)
#pragma unroll
    for (int r = 0; r < 4; ++r) {
      int rowz = m * 16 + l4 * 4 + r;
      float mean = tot_m[rowz], rstd = tot_r[rowz];
#pragma unroll
      for (int n = 0; n < 8; ++n) {
        out[((size_t)v * T_ROWS + row0 + rowz) * D_DIM + wn0 + n * 16 + l15] =
            packf((acc[m][n][r] - mean) * rstd * w2v[n] + b2v[n]);
      }
    }
}

// ---------------- out = LN3(x + x@W^T + pb), barrier-free MFMA, in place ---
// 2048 blocks x 256 thr; 64 rows x full 512 cols; K=512 in 16 steps of 32.
// A (x packed) and B (W packed) streamed from global; no LDS in main loop.
__global__ __launch_bounds__(256, 2) void fgemm_kernel(
    const uint32_t* __restrict__ Wp, const float* __restrict__ pb,
    const float* __restrict__ w3, const float* __restrict__ b3,
    uint32_t* __restrict__ io) {
  __shared__ float red_s[64][4];
  __shared__ float red_q[64][4];
  __shared__ float tot_m[64];
  __shared__ float tot_r[64];
  const int tid = threadIdx.x;
  const int lane = tid & 63;
  const int wv = tid >> 6;
  const int l15 = lane & 15;
  const int l4 = lane >> 4;
  const int wn0 = wv * 128;
  const size_t row0 = (size_t)blockIdx.x * 64;

  const uint32_t* aB = io + (row0 + l15) * D_DIM + l4 * 8;
  const uint32_t* bB = Wp + (size_t)(wn0 + l15) * D_DIM + l4 * 8;

  floatx4 acc[4][8];
#pragma unroll
  for (int m = 0; m < 4; ++m)
#pragma unroll
    for (int n = 0; n < 8; ++n) acc[m][n] = (floatx4){0.f, 0.f, 0.f, 0.f};

#pragma unroll 2
  for (int kt = 0; kt < 16; ++kt) {
    const int k0 = kt * 32;
    shortx8 afh[4], afl[4];
#pragma unroll
    for (int m = 0; m < 4; ++m) {
      const uint32_t* p = aB + m * (16 * D_DIM) + k0;
      unpack8(*(const uint4*)p, *(const uint4*)(p + 4), &afh[m], &afl[m]);
    }
#pragma unroll
    for (int n = 0; n < 8; ++n) {
      const uint32_t* q = bB + n * (16 * D_DIM) + k0;
      shortx8 bfh, bfl;
      unpack8(*(const uint4*)q, *(const uint4*)(q + 4), &bfh, &bfl);
#pragma unroll
      for (int m = 0; m < 4; ++m) {
        acc[m][n] = __builtin_amdgcn_mfma_f32_16x16x32_bf16(afh[m], bfh, acc[m][n], 0, 0, 0);
        acc[m][n] = __builtin_amdgcn_mfma_f32_16x16x32_bf16(afl[m], bfh, acc[m][n], 0, 0, 0);
        acc[m][n] = __builtin_amdgcn_mfma_f32_16x16x32_bf16(afh[m], bfl, acc[m][n], 0, 0, 0);
      }
    }
  }

  // epilogue: z = x + gemm + pb; fused LN3; write fp32 over io
  float pbv[8], w3v[8], b3v[8];
#pragma unroll
  for (int n = 0; n < 8; ++n) {
    int col = wn0 + n * 16 + l15;
    pbv[n] = pb[col]; w3v[n] = w3[col]; b3v[n] = b3[col];
  }
  float ps[4][4], pq[4][4];
#pragma unroll
  for (int m = 0; m < 4; ++m)
#pragma unroll
    for (int r = 0; r < 4; ++r) { ps[m][r] = 0.f; pq[m][r] = 0.f; }
#pragma unroll
  for (int m = 0; m < 4; ++m) {
#pragma unroll
    for (int r = 0; r < 4; ++r) {
      int rowz = m * 16 + l4 * 4 + r;
#pragma unroll
      for (int n = 0; n < 8; ++n) {
        uint32_t xp = io[(row0 + rowz) * D_DIM + wn0 + n * 16 + l15];
        float z = unpackf(xp) + acc[m][n][r] + pbv[n];
        acc[m][n][r] = z;
        ps[m][r] += z;
        pq[m][r] += z * z;
      }
    }
  }
#pragma unroll
  for (int m = 0; m < 4; ++m) {
#pragma unroll
    for (int r = 0; r < 4; ++r) {
      float s = ps[m][r], q = pq[m][r];
      s += __shfl_xor(s, 1); s += __shfl_xor(s, 2);
      s += __shfl_xor(s, 4); s += __shfl_xor(s, 8);
      q += __shfl_xor(q, 1); q += __shfl_xor(q, 2);
      q += __shfl_xor(q, 4); q += __shfl_xor(q, 8);
      if (l15 == 0) {
        red_s[m * 16 + l4 * 4 + r][wv] = s;
        red_q[m * 16 + l4 * 4 + r][wv] = q;
      }
    }
  }
  __syncthreads();
  if (tid < 64) {
    float s = red_s[tid][0] + red_s[tid][1] + red_s[tid][2] + red_s[tid][3];
    float q = red_q[tid][0] + red_q[tid][1] + red_q[tid][2] + red_q[tid][3];
    float mean = s * (1.0f / D_DIM);
    float var = q * (1.0f / D_DIM) - mean * mean;
    tot_m[tid] = mean;
    tot_r[tid] = rsqrtf(var + LNE);
  }
  __syncthreads();
  float* of = (float*)io;
#pragma unroll
  for (int m = 0; m < 4; ++m) {
#pragma unroll
    for (int r = 0; r < 4; ++r) {
      int rowz = m * 16 + l4 * 4 + r;
      float mean = tot_m[rowz], rstd = tot_r[rowz];
#pragma unroll
      for (int n = 0; n < 8; ++n) {
        of[(row0 + rowz) * D_DIM + wn0 + n * 16 + l15] =
            (acc[m][n][r] - mean) * rstd * w3v[n] + b3v[n];
      }
    }
  }
}

extern "C" void kernel_launch(void* const* d_in, const int* in_sizes, int n_in,
                              void* d_out, int out_size, void* d_ws, size_t ws_size,
                              hipStream_t stream) {
  const float* text  = (const float*)d_in[0];
  const float* video = (const float*)d_in[1];
  const float* ln1w  = (const float*)d_in[2];
  const float* ln1b  = (const float*)d_in[3];
  const float* ln2w  = (const float*)d_in[4];
  const float* ln2b  = (const float*)d_in[5];
  const float* ln3w  = (const float*)d_in[6];
  const float* ln3b  = (const float*)d_in[7];
  const float* projw = (const float*)d_in[8];
  const float* projb = (const float*)d_in[9];
  float* ws  = (float*)d_ws;

  float* t_ln  = ws;                   // 512*512          = 262144 f
  float* vd_ln = t_ln + 262144;        // 256*64*512       = 8388608 f (becomes vdTp)
  float* gram  = vd_ln + 8388608;      // 256*64*64        = 1048576 f
  float* attn  = gram + 1048576;       // 256*512*64       = 8388608 f (fp32 sims -> packed attn)
  uint32_t* Wp = (uint32_t*)(attn + 8388608);  // 512*512 u32 packed
  // total 18,350,080 x 4B = 73.4 MB of d_ws

  ln_kernel<<<128, 256, 0, stream>>>(text, ln1w, ln1b, t_ln, 512);
  ln_kernel<<<4096, 256, 0, stream>>>(video, ln1w, ln1b, vd_ln, 16384);
  convw_kernel<<<256, 256, 0, stream>>>(projw, Wp);
  sims_kernel<<<dim3(8, 256), 256, 0, stream>>>(t_ln, vd_ln, attn);
  gram_kernel<<<256, 256, 0, stream>>>(vd_ln, gram);
  vdt_kernel<<<256, 256, 0, stream>>>(vd_ln);   // vd_ln -> packed vd^T, in place
  nmf_kernel<<<256, 512, 0, stream>>>(gram, attn, (uint32_t*)attn);
  attnout_kernel<<<dim3(8, 256), 256, 0, stream>>>((uint32_t*)attn, (uint32_t*)vd_ln,
                                                   ln2w, ln2b, (uint32_t*)d_out);
  fgemm_kernel<<<2048, 256, 0, stream>>>(Wp, projb, ln3w, ln3b, (uint32_t*)d_out);
}

// Round 6
// 1098.541 us; speedup vs baseline: 2.4248x; 1.2221x over previous
//
#include <hip/hip_runtime.h>
#include <math.h>

#define T_ROWS 512
#define V_NUM  256
#define F_NUM  64
#define D_DIM  512
#define NM_EPS 1e-6f
#define LNE    1e-5f
#define ETA    0.015f

typedef __attribute__((ext_vector_type(8))) short shortx8;
typedef __attribute__((ext_vector_type(4))) float floatx4;

__device__ __forceinline__ float wave_sum(float x) {
#pragma unroll
  for (int off = 32; off > 0; off >>= 1) x += __shfl_xor(x, off);
  return x;
}

// bf16 round-to-nearest-even split helpers
__device__ __forceinline__ uint32_t bf_hi(float f) {
  uint32_t u = __float_as_uint(f);
  return (u + 0x7fffu + ((u >> 16) & 1u)) >> 16;
}
__device__ __forceinline__ uint32_t packf(float f) {
  uint32_t h = bf_hi(f);
  float rem = f - __uint_as_float(h << 16);
  uint32_t l = bf_hi(rem);
  return (h << 16) | l;
}
__device__ __forceinline__ float unpackf(uint32_t p) {
  return __uint_as_float(p & 0xffff0000u) + __uint_as_float(p << 16);
}
// 8 packed u32 (8 k-elements) -> hi/lo shortx8 MFMA fragments
__device__ __forceinline__ void unpack8(uint4 a, uint4 b, shortx8* h, shortx8* l) {
  uint4 hu, lu;
  hu.x = (a.x >> 16) | (a.y & 0xffff0000u);
  hu.y = (a.z >> 16) | (a.w & 0xffff0000u);
  hu.z = (b.x >> 16) | (b.y & 0xffff0000u);
  hu.w = (b.z >> 16) | (b.w & 0xffff0000u);
  lu.x = (a.x & 0xffffu) | (a.y << 16);
  lu.y = (a.z & 0xffffu) | (a.w << 16);
  lu.z = (b.x & 0xffffu) | (b.y << 16);
  lu.w = (b.z & 0xffffu) | (b.w << 16);
  *h = *(shortx8*)&hu;
  *l = *(shortx8*)&lu;
}

// async 16B global -> LDS copy (wave-uniform LDS base + lane*16 dest)
__device__ __forceinline__ void gload16(void* lds, const void* g) {
  __builtin_amdgcn_global_load_lds(
      (const __attribute__((address_space(1))) void*)g,
      (__attribute__((address_space(3))) void*)lds, 16, 0, 0);
}

// ---------------- LayerNorm over last dim (512); one wave per row ----------
__global__ __launch_bounds__(256) void ln_kernel(
    const float* __restrict__ in, const float* __restrict__ w,
    const float* __restrict__ b, float* __restrict__ out, int rows) {
  int lane = threadIdx.x & 63;
  int row  = (blockIdx.x << 2) + (threadIdx.x >> 6);
  if (row >= rows) return;
  const float4* x4 = (const float4*)(in + (size_t)row * D_DIM);
  float4 v0 = x4[lane * 2 + 0];
  float4 v1 = x4[lane * 2 + 1];
  float s = v0.x + v0.y + v0.z + v0.w + v1.x + v1.y + v1.z + v1.w;
  s = wave_sum(s);
  float m = s * (1.0f / D_DIM);
  float d0 = v0.x - m, d1 = v0.y - m, d2 = v0.z - m, d3 = v0.w - m;
  float d4 = v1.x - m, d5 = v1.y - m, d6 = v1.z - m, d7 = v1.w - m;
  float q = d0*d0 + d1*d1 + d2*d2 + d3*d3 + d4*d4 + d5*d5 + d6*d6 + d7*d7;
  q = wave_sum(q);
  float rstd = rsqrtf(q * (1.0f / D_DIM) + LNE);
  const float4* w4 = (const float4*)w;
  const float4* b4 = (const float4*)b;
  float4 W0 = w4[lane*2+0], W1 = w4[lane*2+1];
  float4 B0 = b4[lane*2+0], B1 = b4[lane*2+1];
  float4 o0, o1;
  o0.x = d0*rstd*W0.x + B0.x; o0.y = d1*rstd*W0.y + B0.y;
  o0.z = d2*rstd*W0.z + B0.z; o0.w = d3*rstd*W0.w + B0.w;
  o1.x = d4*rstd*W1.x + B1.x; o1.y = d5*rstd*W1.y + B1.y;
  o1.z = d6*rstd*W1.z + B1.z; o1.w = d7*rstd*W1.w + B1.w;
  float4* y4 = (float4*)(out + (size_t)row * D_DIM);
  y4[lane*2+0] = o0; y4[lane*2+1] = o1;
}

// ---------------- pack proj_w fp32 -> u32 (bf16 hi<<16 | lo) ---------------
__global__ __launch_bounds__(256) void convw_kernel(
    const float* __restrict__ W, uint32_t* __restrict__ Wp) {
  int i = (blockIdx.x * 256 + threadIdx.x) * 4;
  float4 v = *(const float4*)(W + i);
  uint4 o;
  o.x = packf(v.x); o.y = packf(v.y); o.z = packf(v.z); o.w = packf(v.w);
  *(uint4*)(Wp + i) = o;
}

// ---------------- sims[v][t][f] = sum_d t_ln[t][d] * vd[v][f][d] -----------
__global__ __launch_bounds__(256) void sims_kernel(
    const float* __restrict__ tmat, const float* __restrict__ vd,
    float* __restrict__ sims) {
  __shared__ float As[64][65];
  __shared__ float Bs[64][65];
  int v = blockIdx.y, mt = blockIdx.x;
  int tid = threadIdx.x;
  int trow = tid >> 4, tcol = tid & 15;
  const float* A = tmat + (size_t)mt * 64 * D_DIM;
  const float* B = vd + (size_t)v * F_NUM * D_DIM;
  float acc[4][4] = {};
  for (int k0 = 0; k0 < D_DIM; k0 += 64) {
#pragma unroll
    for (int l = 0; l < 4; ++l) {
      int idx = l * 256 + tid;
      int r = idx >> 4, c = (idx & 15) * 4;
      float4 av = *(const float4*)(A + (size_t)r * D_DIM + k0 + c);
      As[r][c+0] = av.x; As[r][c+1] = av.y; As[r][c+2] = av.z; As[r][c+3] = av.w;
      float4 bv = *(const float4*)(B + (size_t)r * D_DIM + k0 + c);
      Bs[r][c+0] = bv.x; Bs[r][c+1] = bv.y; Bs[r][c+2] = bv.z; Bs[r][c+3] = bv.w;
    }
    __syncthreads();
#pragma unroll 8
    for (int k = 0; k < 64; ++k) {
      float a0 = As[trow*4+0][k], a1 = As[trow*4+1][k];
      float a2 = As[trow*4+2][k], a3 = As[trow*4+3][k];
      float b0 = Bs[tcol*4+0][k], b1 = Bs[tcol*4+1][k];
      float b2 = Bs[tcol*4+2][k], b3 = Bs[tcol*4+3][k];
      acc[0][0] += a0*b0; acc[0][1] += a0*b1; acc[0][2] += a0*b2; acc[0][3] += a0*b3;
      acc[1][0] += a1*b0; acc[1][1] += a1*b1; acc[1][2] += a1*b2; acc[1][3] += a1*b3;
      acc[2][0] += a2*b0; acc[2][1] += a2*b1; acc[2][2] += a2*b2; acc[2][3] += a2*b3;
      acc[3][0] += a3*b0; acc[3][1] += a3*b1; acc[3][2] += a3*b2; acc[3][3] += a3*b3;
    }
    __syncthreads();
  }
  float* C = sims + ((size_t)v * T_ROWS + mt * 64) * F_NUM;
#pragma unroll
  for (int i = 0; i < 4; ++i) {
    float4 o = make_float4(acc[i][0], acc[i][1], acc[i][2], acc[i][3]);
    *(float4*)(C + (size_t)(trow*4+i) * F_NUM + tcol*4) = o;
  }
}

// ---------------- gram[v][m][n] = sum_d vd[v][m][d]*vd[v][n][d] ------------
__global__ __launch_bounds__(256) void gram_kernel(
    const float* __restrict__ vd, float* __restrict__ gram) {
  __shared__ float As[64][65];
  int v = blockIdx.x;
  int tid = threadIdx.x;
  int trow = tid >> 4, tcol = tid & 15;
  const float* A = vd + (size_t)v * F_NUM * D_DIM;
  float acc[4][4] = {};
  for (int k0 = 0; k0 < D_DIM; k0 += 64) {
#pragma unroll
    for (int l = 0; l < 4; ++l) {
      int idx = l * 256 + tid;
      int r = idx >> 4, c = (idx & 15) * 4;
      float4 av = *(const float4*)(A + (size_t)r * D_DIM + k0 + c);
      As[r][c+0] = av.x; As[r][c+1] = av.y; As[r][c+2] = av.z; As[r][c+3] = av.w;
    }
    __syncthreads();
#pragma unroll 8
    for (int k = 0; k < 64; ++k) {
      float a0 = As[trow*4+0][k], a1 = As[trow*4+1][k];
      float a2 = As[trow*4+2][k], a3 = As[trow*4+3][k];
      float b0 = As[tcol*4+0][k], b1 = As[tcol*4+1][k];
      float b2 = As[tcol*4+2][k], b3 = As[tcol*4+3][k];
      acc[0][0] += a0*b0; acc[0][1] += a0*b1; acc[0][2] += a0*b2; acc[0][3] += a0*b3;
      acc[1][0] += a1*b0; acc[1][1] += a1*b1; acc[1][2] += a1*b2; acc[1][3] += a1*b3;
      acc[2][0] += a2*b0; acc[2][1] += a2*b1; acc[2][2] += a2*b2; acc[2][3] += a2*b3;
      acc[3][0] += a3*b0; acc[3][1] += a3*b1; acc[3][2] += a3*b2; acc[3][3] += a3*b3;
    }
    __syncthreads();
  }
  float* C = gram + (size_t)v * 4096;
#pragma unroll
  for (int i = 0; i < 4; ++i) {
    float4 o = make_float4(acc[i][0], acc[i][1], acc[i][2], acc[i][3]);
    *(float4*)(C + (size_t)(trow*4+i) * F_NUM + tcol*4) = o;
  }
}

// ---------------- vdt: in-place per-v transpose+pack -----------------------
__global__ __launch_bounds__(256) void vdt_kernel(float* __restrict__ vd) {
  __shared__ float tile[64][513];   // ~131.3 KiB
  int v = blockIdx.x;
  int tid = threadIdx.x;
  float* base = vd + (size_t)v * F_NUM * D_DIM;
#pragma unroll
  for (int p = 0; p < 32; ++p) {
    int idx = p * 256 + tid;
    int f = idx >> 7, dq = (idx & 127) * 4;
    float4 x = *(const float4*)(base + (size_t)f * D_DIM + dq);
    tile[f][dq+0] = x.x; tile[f][dq+1] = x.y; tile[f][dq+2] = x.z; tile[f][dq+3] = x.w;
  }
  __syncthreads();
  uint32_t* out = (uint32_t*)base;
#pragma unroll
  for (int p = 0; p < 32; ++p) {
    int idx = p * 256 + tid;
    int d = idx >> 4, fq = (idx & 15) * 4;
    uint4 o;
    o.x = packf(tile[fq+0][d]); o.y = packf(tile[fq+1][d]);
    o.z = packf(tile[fq+2][d]); o.w = packf(tile[fq+3][d]);
    *(uint4*)(out + (size_t)d * F_NUM + fq) = o;
  }
}

// ---------------- NMF: 10 iters + quad-form norm; emits PACKED attn --------
__global__ __launch_bounds__(512, 2) void nmf_kernel(
    const float* __restrict__ gram, const float* __restrict__ sims_in,
    uint32_t* __restrict__ attn_out) {
  __shared__ float G[64 * 64];      // 16 KiB, symmetric
  __shared__ float A[512 * 65];     // 130 KiB
  int tid = threadIdx.x;
  int v = blockIdx.x;
  const float4* g4 = (const float4*)(gram + (size_t)v * 4096);
  ((float4*)G)[tid]       = g4[tid];
  ((float4*)G)[512 + tid] = g4[512 + tid];
  float* ar = &A[tid * 65];
  const float* srow = sims_in + ((size_t)v * T_ROWS + tid) * F_NUM;
  float s[64];
#pragma unroll
  for (int q = 0; q < 16; ++q) {
    float4 t4 = ((const float4*)srow)[q];
    s[q*4+0] = t4.x; s[q*4+1] = t4.y; s[q*4+2] = t4.z; s[q*4+3] = t4.w;
    ar[q*4+0] = t4.x; ar[q*4+1] = t4.y; ar[q*4+2] = t4.z; ar[q*4+3] = t4.w;
  }
  __syncthreads();
  for (int it = 0; it < 10; ++it) {
    float dnm[64];
#pragma unroll
    for (int m = 0; m < 64; ++m) dnm[m] = 0.0f;
    for (int n = 0; n < 64; ++n) {
      float an = ar[n];
      const float* gr = &G[n * 64];
#pragma unroll
      for (int m = 0; m < 64; ++m) dnm[m] += an * gr[m];
    }
#pragma unroll
    for (int m = 0; m < 64; ++m) {
      float xv = ar[m] - ETA * ((dnm[m] + NM_EPS) - s[m]);
      ar[m] = (xv <= 0.0f) ? NM_EPS : xv;
    }
  }
  float t2[64];
#pragma unroll
  for (int m = 0; m < 64; ++m) t2[m] = 0.0f;
  for (int n = 0; n < 64; ++n) {
    float an = ar[n];
    const float* gr = &G[n * 64];
#pragma unroll
    for (int m = 0; m < 64; ++m) t2[m] += an * gr[m];
  }
  float n2 = 0.0f;
#pragma unroll
  for (int m = 0; m < 64; ++m) n2 += ar[m] * t2[m];
  float inv = 1.0f / sqrtf(n2);
  uint32_t* orow = attn_out + ((size_t)v * T_ROWS + tid) * F_NUM;
#pragma unroll
  for (int q = 0; q < 16; ++q) {
    uint4 o;
    o.x = packf(ar[q*4+0]*inv); o.y = packf(ar[q*4+1]*inv);
    o.z = packf(ar[q*4+2]*inv); o.w = packf(ar[q*4+3]*inv);
    *(uint4*)(orow + q*4) = o;
  }
}

// ---------------- attn_out = attn_v @ vd_v (MFMA), fused LN2 -> packed out -
__global__ __launch_bounds__(256, 2) void attnout_kernel(
    const uint32_t* __restrict__ attnp, const uint32_t* __restrict__ vdTp,
    const float* __restrict__ w2, const float* __restrict__ b2,
    uint32_t* __restrict__ out) {
  __shared__ float red_s[64][4];
  __shared__ float red_q[64][4];
  __shared__ float tot_m[64];
  __shared__ float tot_r[64];
  const int tid = threadIdx.x;
  const int lane = tid & 63;
  const int wv = tid >> 6;
  const int l15 = lane & 15;
  const int l4 = lane >> 4;
  const int wn0 = wv * 128;
  const int v = blockIdx.y;
  const int row0 = blockIdx.x * 64;

  const uint32_t* aB = attnp + ((size_t)v * T_ROWS + row0 + l15) * F_NUM + l4 * 8;
  const uint32_t* bB = vdTp + ((size_t)v * D_DIM + wn0 + l15) * F_NUM + l4 * 8;

  floatx4 acc[4][8];
#pragma unroll
  for (int m = 0; m < 4; ++m)
#pragma unroll
    for (int n = 0; n < 8; ++n) acc[m][n] = (floatx4){0.f, 0.f, 0.f, 0.f};

#pragma unroll
  for (int ks = 0; ks < 2; ++ks) {
    const int k0 = ks * 32;
    shortx8 afh[4], afl[4];
#pragma unroll
    for (int m = 0; m < 4; ++m) {
      const uint32_t* p = aB + m * (16 * F_NUM) + k0;
      unpack8(*(const uint4*)p, *(const uint4*)(p + 4), &afh[m], &afl[m]);
    }
#pragma unroll
    for (int n = 0; n < 8; ++n) {
      const uint32_t* q = bB + n * (16 * F_NUM) + k0;
      shortx8 bfh, bfl;
      unpack8(*(const uint4*)q, *(const uint4*)(q + 4), &bfh, &bfl);
#pragma unroll
      for (int m = 0; m < 4; ++m) {
        acc[m][n] = __builtin_amdgcn_mfma_f32_16x16x32_bf16(afh[m], bfh, acc[m][n], 0, 0, 0);
        acc[m][n] = __builtin_amdgcn_mfma_f32_16x16x32_bf16(afl[m], bfh, acc[m][n], 0, 0, 0);
        acc[m][n] = __builtin_amdgcn_mfma_f32_16x16x32_bf16(afh[m], bfl, acc[m][n], 0, 0, 0);
      }
    }
  }

  float w2v[8], b2v[8];
#pragma unroll
  for (int n = 0; n < 8; ++n) {
    int col = wn0 + n * 16 + l15;
    w2v[n] = w2[col]; b2v[n] = b2[col];
  }
  float ps[4][4], pq[4][4];
#pragma unroll
  for (int m = 0; m < 4; ++m)
#pragma unroll
    for (int r = 0; r < 4; ++r) { ps[m][r] = 0.f; pq[m][r] = 0.f; }
#pragma unroll
  for (int m = 0; m < 4; ++m)
#pragma unroll
    for (int r = 0; r < 4; ++r)
#pragma unroll
      for (int n = 0; n < 8; ++n) {
        float z = acc[m][n][r];
        ps[m][r] += z; pq[m][r] += z * z;
      }
#pragma unroll
  for (int m = 0; m < 4; ++m)
#pragma unroll
    for (int r = 0; r < 4; ++r) {
      float s = ps[m][r], q = pq[m][r];
      s += __shfl_xor(s, 1); s += __shfl_xor(s, 2);
      s += __shfl_xor(s, 4); s += __shfl_xor(s, 8);
      q += __shfl_xor(q, 1); q += __shfl_xor(q, 2);
      q += __shfl_xor(q, 4); q += __shfl_xor(q, 8);
      if (l15 == 0) {
        red_s[m * 16 + l4 * 4 + r][wv] = s;
        red_q[m * 16 + l4 * 4 + r][wv] = q;
      }
    }
  __syncthreads();
  if (tid < 64) {
    float s = red_s[tid][0] + red_s[tid][1] + red_s[tid][2] + red_s[tid][3];
    float q = red_q[tid][0] + red_q[tid][1] + red_q[tid][2] + red_q[tid][3];
    float mean = s * (1.0f / D_DIM);
    float var = q * (1.0f / D_DIM) - mean * mean;
    tot_m[tid] = mean;
    tot_r[tid] = rsqrtf(var + LNE);
  }
  __syncthreads();
#pragma unroll
  for (int m = 0; m < 4; ++m)
#pragma unroll
    for (int r = 0; r < 4; ++r) {
      int rowz = m * 16 + l4 * 4 + r;
      float mean = tot_m[rowz], rstd = tot_r[rowz];
#pragma unroll
      for (int n = 0; n < 8; ++n) {
        out[((size_t)v * T_ROWS + row0 + rowz) * D_DIM + wn0 + n * 16 + l15] =
            packf((acc[m][n][r] - mean) * rstd * w2v[n] + b2v[n]);
      }
    }
}

// ---------------- out = LN3(x + x@W^T + pb), m97-style staged MFMA ---------
// 2048 blocks x 512 thr (8 waves). Tile 64 rows x full 512 cols, BK=32 (16
// steps). Both tiles staged packed-u32 via async global_load_lds (width 16,
// linear dest); k-slot XOR swizzle (slot ^ (row&7)) applied on the GLOBAL
// source and on ds_read (G21) -> bank-balanced b128 reads. LN3 fused.
__global__ __launch_bounds__(512, 4) void fgemm_kernel(
    const uint32_t* __restrict__ Wp, const float* __restrict__ pb,
    const float* __restrict__ w3, const float* __restrict__ b3,
    uint32_t* __restrict__ io) {
  __shared__ uint32_t Bs[512 * 32];   // 64 KiB packed W tile
  __shared__ uint32_t As[64 * 32];    // 8 KiB packed x tile
  __shared__ float red_s[64][8];
  __shared__ float red_q[64][8];
  __shared__ float tot_m[64];
  __shared__ float tot_r[64];

  const int tid = threadIdx.x;
  const int w = tid >> 6;            // wave 0..7 -> col block of 64
  const int l = tid & 63;
  const int l15 = l & 15;
  const int l4 = l >> 4;
  const int wn0 = w * 64;
  const size_t row0 = (size_t)blockIdx.x * 64;

  // staging geometry: each 1KB instr = 8 rows x 8 slots(16B); lane l ->
  // row +(l>>3), phys slot l&7; source k-octet = (l&7) ^ (l>>3) (swizzle)
  const int sr = l >> 3;
  const int ss = (l & 7) ^ sr;
  const uint32_t* bsrc = Wp + (size_t)(w * 64 + sr) * D_DIM + ss * 4;
  const uint32_t* asrc = io + (row0 + w * 8 + sr) * D_DIM + ss * 4;
  uint32_t* bdst = &Bs[(w * 64) * 32];
  uint32_t* adst = &As[(w * 8) * 32];

  // ds_read physical slots for this lane's fragment (swizzled)
  const int p0 = (l4 * 2)     ^ (l15 & 7);
  const int p1 = (l4 * 2 + 1) ^ (l15 & 7);

  floatx4 acc[4][4];
#pragma unroll
  for (int m = 0; m < 4; ++m)
#pragma unroll
    for (int n = 0; n < 4; ++n) acc[m][n] = (floatx4){0.f, 0.f, 0.f, 0.f};

  for (int kt = 0; kt < 16; ++kt) {
    const int k0 = kt * 32;
    // ---- async stage: 8x1KB of B + 1x1KB of A per wave
#pragma unroll
    for (int i = 0; i < 8; ++i)
      gload16(bdst + i * (8 * 32), bsrc + (size_t)i * (8 * D_DIM) + k0);
    gload16(adst, asrc + k0);
    __syncthreads();   // compiler drains vmcnt before barrier
    // ---- compute: m split 2+2 to bound live VGPRs
#pragma unroll
    for (int mh = 0; mh < 2; ++mh) {
      shortx8 afh[2], afl[2];
#pragma unroll
      for (int mm = 0; mm < 2; ++mm) {
        int ra = (mh * 2 + mm) * 16 + l15;
        uint4 a = *(const uint4*)&As[ra * 32 + p0 * 4];
        uint4 b = *(const uint4*)&As[ra * 32 + p1 * 4];
        unpack8(a, b, &afh[mm], &afl[mm]);
      }
#pragma unroll
      for (int n = 0; n < 4; ++n) {
        int rb = wn0 + n * 16 + l15;
        uint4 a = *(const uint4*)&Bs[rb * 32 + p0 * 4];
        uint4 b = *(const uint4*)&Bs[rb * 32 + p1 * 4];
        shortx8 bfh, bfl;
        unpack8(a, b, &bfh, &bfl);
#pragma unroll
        for (int mm = 0; mm < 2; ++mm) {
          int m = mh * 2 + mm;
          acc[m][n] = __builtin_amdgcn_mfma_f32_16x16x32_bf16(afh[mm], bfh, acc[m][n], 0, 0, 0);
          acc[m][n] = __builtin_amdgcn_mfma_f32_16x16x32_bf16(afl[mm], bfh, acc[m][n], 0, 0, 0);
          acc[m][n] = __builtin_amdgcn_mfma_f32_16x16x32_bf16(afh[mm], bfl, acc[m][n], 0, 0, 0);
        }
      }
    }
    __syncthreads();
  }

  // ---- epilogue: z = x + gemm + pb; fused LN3; write fp32 over io ----
  float pbv[4], w3v[4], b3v[4];
#pragma unroll
  for (int n = 0; n < 4; ++n) {
    int col = wn0 + n * 16 + l15;
    pbv[n] = pb[col]; w3v[n] = w3[col]; b3v[n] = b3[col];
  }
  float ps[4][4], pq[4][4];
#pragma unroll
  for (int m = 0; m < 4; ++m)
#pragma unroll
    for (int r = 0; r < 4; ++r) { ps[m][r] = 0.f; pq[m][r] = 0.f; }
#pragma unroll
  for (int m = 0; m < 4; ++m) {
#pragma unroll
    for (int r = 0; r < 4; ++r) {
      int rowz = m * 16 + l4 * 4 + r;
#pragma unroll
      for (int n = 0; n < 4; ++n) {
        uint32_t xp = io[(row0 + rowz) * D_DIM + wn0 + n * 16 + l15];
        float z = unpackf(xp) + acc[m][n][r] + pbv[n];
        acc[m][n][r] = z;
        ps[m][r] += z;
        pq[m][r] += z * z;
      }
    }
  }
#pragma unroll
  for (int m = 0; m < 4; ++m) {
#pragma unroll
    for (int r = 0; r < 4; ++r) {
      float s = ps[m][r], q = pq[m][r];
      s += __shfl_xor(s, 1); s += __shfl_xor(s, 2);
      s += __shfl_xor(s, 4); s += __shfl_xor(s, 8);
      q += __shfl_xor(q, 1); q += __shfl_xor(q, 2);
      q += __shfl_xor(q, 4); q += __shfl_xor(q, 8);
      if (l15 == 0) {
        red_s[m * 16 + l4 * 4 + r][w] = s;
        red_q[m * 16 + l4 * 4 + r][w] = q;
      }
    }
  }
  __syncthreads();
  if (tid < 64) {
    float s = 0.f, q = 0.f;
#pragma unroll
    for (int i = 0; i < 8; ++i) { s += red_s[tid][i]; q += red_q[tid][i]; }
    float mean = s * (1.0f / D_DIM);
    float var = q * (1.0f / D_DIM) - mean * mean;
    tot_m[tid] = mean;
    tot_r[tid] = rsqrtf(var + LNE);
  }
  __syncthreads();
  float* of = (float*)io;
#pragma unroll
  for (int m = 0; m < 4; ++m) {
#pragma unroll
    for (int r = 0; r < 4; ++r) {
      int rowz = m * 16 + l4 * 4 + r;
      float mean = tot_m[rowz], rstd = tot_r[rowz];
#pragma unroll
      for (int n = 0; n < 4; ++n) {
        of[(row0 + rowz) * D_DIM + wn0 + n * 16 + l15] =
            (acc[m][n][r] - mean) * rstd * w3v[n] + b3v[n];
      }
    }
  }
}

extern "C" void kernel_launch(void* const* d_in, const int* in_sizes, int n_in,
                              void* d_out, int out_size, void* d_ws, size_t ws_size,
                              hipStream_t stream) {
  const float* text  = (const float*)d_in[0];
  const float* video = (const float*)d_in[1];
  const float* ln1w  = (const float*)d_in[2];
  const float* ln1b  = (const float*)d_in[3];
  const float* ln2w  = (const float*)d_in[4];
  const float* ln2b  = (const float*)d_in[5];
  const float* ln3w  = (const float*)d_in[6];
  const float* ln3b  = (const float*)d_in[7];
  const float* projw = (const float*)d_in[8];
  const float* projb = (const float*)d_in[9];
  float* ws  = (float*)d_ws;

  float* t_ln  = ws;                   // 512*512          = 262144 f
  float* vd_ln = t_ln + 262144;        // 256*64*512       = 8388608 f (becomes vdTp)
  float* gram  = vd_ln + 8388608;      // 256*64*64        = 1048576 f
  float* attn  = gram + 1048576;       // 256*512*64       = 8388608 f (fp32 sims -> packed attn)
  uint32_t* Wp = (uint32_t*)(attn + 8388608);  // 512*512 u32 packed
  // total 18,350,080 x 4B = 73.4 MB of d_ws

  ln_kernel<<<128, 256, 0, stream>>>(text, ln1w, ln1b, t_ln, 512);
  ln_kernel<<<4096, 256, 0, stream>>>(video, ln1w, ln1b, vd_ln, 16384);
  convw_kernel<<<256, 256, 0, stream>>>(projw, Wp);
  sims_kernel<<<dim3(8, 256), 256, 0, stream>>>(t_ln, vd_ln, attn);
  gram_kernel<<<256, 256, 0, stream>>>(vd_ln, gram);
  vdt_kernel<<<256, 256, 0, stream>>>(vd_ln);   // vd_ln -> packed vd^T, in place
  nmf_kernel<<<256, 512, 0, stream>>>(gram, attn, (uint32_t*)attn);
  attnout_kernel<<<dim3(8, 256), 256, 0, stream>>>((uint32_t*)attn, (uint32_t*)vd_ln,
                                                   ln2w, ln2b, (uint32_t*)d_out);
  fgemm_kernel<<<2048, 512, 0, stream>>>(Wp, projb, ln3w, ln3b, (uint32_t*)d_out);
}